// Round 4
// baseline (879.161 us; speedup 1.0000x reference)
//
#include <hip/hip_runtime.h>
#include <hip/hip_bf16.h>
#include <math.h>

typedef unsigned short u16;
typedef __attribute__((ext_vector_type(8))) short short8;
typedef __attribute__((ext_vector_type(4))) float f32x4;

constexpr int Bc = 4, Tt = 2048, Dd = 768, Hh = 12, Hd = 64, Df = 3072;
constexpr int BT = Bc * Tt;  // 8192

__device__ __forceinline__ u16 f2b(float x) {
  __hip_bfloat16 h = __float2bfloat16(x);
  return *reinterpret_cast<u16*>(&h);
}
__device__ __forceinline__ float gelu_exact(float g) {
  return 0.5f * g * (1.0f + erff(g * 0.70710678118654752440f));
}
__device__ __forceinline__ void gload16(const void* g, void* l) {
  __builtin_amdgcn_global_load_lds(
      (const __attribute__((address_space(1))) unsigned int*)g,
      (__attribute__((address_space(3))) unsigned int*)l, 16, 0, 0);
}

// ---------------------------------------------------------------------------
// 32x32 transpose tile: in [R][C] fp32 -> out [C][R] bf16
// ---------------------------------------------------------------------------
__device__ __forceinline__ void tr_tile(const float* __restrict__ in,
                                        u16* __restrict__ out, int R, int C,
                                        int bx, int by, float* sh) {
  const int tx = threadIdx.x & 31, ty = threadIdx.x >> 5;
  const int r0 = by * 32, c0 = bx * 32;
#pragma unroll
  for (int i = 0; i < 4; ++i)
    sh[(ty + i * 8) * 33 + tx] = in[(size_t)(r0 + ty + i * 8) * C + c0 + tx];
  __syncthreads();
#pragma unroll
  for (int i = 0; i < 4; ++i)
    out[(size_t)(c0 + ty + i * 8) * R + r0 + tx] = f2b(sh[tx * 33 + ty + i * 8]);
}

// ---------------------------------------------------------------------------
// One fused prep kernel, dispatched by block range:
//   [0,3072)      x -> bf16
//   [3072,3648)   Wq^T   [3648,4224) Wk^T   [4224,4800) Wv^T  (into wqkvT)
//   [4800,5376)   Wo^T
//   [5376,7680)   W1^T (768x3072)
//   [7680,9984)   W2^T (3072x768)
//   [9984,10025)  biasc = bq|bk|bv ; maskf = mask ? 0 : -1e30
// ---------------------------------------------------------------------------
__global__ __launch_bounds__(256) void prep_all(
    const float* __restrict__ x, const float* __restrict__ Wq,
    const float* __restrict__ Wk, const float* __restrict__ Wv,
    const float* __restrict__ Wo, const float* __restrict__ W1,
    const float* __restrict__ W2, const float* __restrict__ bq,
    const float* __restrict__ bk, const float* __restrict__ bv,
    const int* __restrict__ mask, u16* __restrict__ xb,
    u16* __restrict__ wqkvT, u16* __restrict__ woT, u16* __restrict__ w1T,
    u16* __restrict__ w2T, float* __restrict__ biasc,
    float* __restrict__ maskf) {
  __shared__ float sh[32 * 33];
  const int s = blockIdx.x;
  if (s < 3072) {
    int i = (s * 256 + threadIdx.x) * 8;
    float4 a = *(const float4*)&x[i];
    float4 b = *(const float4*)&x[i + 4];
    u16 t[8] = {f2b(a.x), f2b(a.y), f2b(a.z), f2b(a.w),
                f2b(b.x), f2b(b.y), f2b(b.z), f2b(b.w)};
    *(uint4*)&xb[i] = *(uint4*)t;
  } else if (s < 3648) {
    int u = s - 3072; tr_tile(Wq, wqkvT, Dd, Dd, u % 24, u / 24, sh);
  } else if (s < 4224) {
    int u = s - 3648; tr_tile(Wk, wqkvT + 768 * Dd, Dd, Dd, u % 24, u / 24, sh);
  } else if (s < 4800) {
    int u = s - 4224; tr_tile(Wv, wqkvT + 1536 * Dd, Dd, Dd, u % 24, u / 24, sh);
  } else if (s < 5376) {
    int u = s - 4800; tr_tile(Wo, woT, Dd, Dd, u % 24, u / 24, sh);
  } else if (s < 7680) {
    int u = s - 5376; tr_tile(W1, w1T, Dd, Df, u % 96, u / 96, sh);
  } else if (s < 9984) {
    int u = s - 7680; tr_tile(W2, w2T, Df, Dd, u % 24, u / 24, sh);
  } else {
    int i = (s - 9984) * 256 + threadIdx.x;
    if (i < 2304)
      biasc[i] = (i < 768) ? bq[i] : (i < 1536) ? bk[i - 768] : bv[i - 1536];
    int j = i - 2304;
    if (j >= 0 && j < BT) maskf[j] = mask[j] ? 0.f : -1e30f;
  }
}

// ---------------------------------------------------------------------------
// bf16 MFMA NT GEMM, 128x128 tile, BK=32, 4 waves.
// MODE 5: QKV fused (N=2304): Q split-head | K split-head | V^T [B,H,64,T]
// MODE 2: C0 fp32 h = add + acc + bias; C1 bf16 h  (Wo, A gathered split-head)
// MODE 3: C0 bf16 gelu(acc + bias)                 (FF1)
// MODE 4: C0 fp32 add + acc + bias                 (FF2)
// ---------------------------------------------------------------------------
template <int MODE>
__global__ __launch_bounds__(256) void mgemm(
    const u16* __restrict__ A, const u16* __restrict__ Bt,
    const float* __restrict__ bias, const float* __restrict__ add,
    void* __restrict__ C0, void* __restrict__ C1, void* __restrict__ C2,
    int K, int N) {
  __shared__ __align__(16) u16 As[128 * 32];
  __shared__ __align__(16) u16 Bs[128 * 32];
  const int tid = threadIdx.x;
  const int lane = tid & 63, wv = tid >> 6;
  const int m0 = blockIdx.y * 128, n0 = blockIdx.x * 128;
  const int wm = (wv >> 1) * 64, wn = (wv & 1) * 64;

  f32x4 acc[4][4] = {};

  for (int k0 = 0; k0 < K; k0 += 32) {
#pragma unroll
    for (int i = 0; i < 2; ++i) {
      const int idx = i * 256 + tid;
      const int row = idx >> 2;
      const int kc = (idx & 3) * 8;
      const u16* ga;
      if constexpr (MODE == 2) {
        const int m = m0 + row, b = m >> 11, t = m & 2047;
        const int kk = k0 + kc, head = kk >> 6, d = kk & 63;
        ga = &A[(((size_t)(b * Hh + head) * Tt + t) << 6) + d];
      } else {
        ga = &A[(size_t)(m0 + row) * K + k0 + kc];
      }
      gload16(ga, &As[idx * 8]);
      gload16(&Bt[(size_t)(n0 + row) * K + k0 + kc], &Bs[idx * 8]);
    }
    __syncthreads();
    short8 af[4], bfr[4];
#pragma unroll
    for (int i = 0; i < 4; ++i) {
      af[i] = *reinterpret_cast<const short8*>(
          &As[(wm + i * 16 + (lane & 15)) * 32 + (lane >> 4) * 8]);
      bfr[i] = *reinterpret_cast<const short8*>(
          &Bs[(wn + i * 16 + (lane & 15)) * 32 + (lane >> 4) * 8]);
    }
#pragma unroll
    for (int i = 0; i < 4; ++i)
#pragma unroll
      for (int j = 0; j < 4; ++j)
        acc[i][j] = __builtin_amdgcn_mfma_f32_16x16x32_bf16(af[i], bfr[j],
                                                            acc[i][j], 0, 0, 0);
    __syncthreads();
  }

  const int lr = (lane >> 4) * 4, lc = lane & 15;
#pragma unroll
  for (int i = 0; i < 4; ++i) {
    const int mbase = m0 + wm + i * 16 + lr;
#pragma unroll
    for (int j = 0; j < 4; ++j) {
      const int col = n0 + wn + j * 16 + lc;
      const float bvs = bias[col];
#pragma unroll
      for (int r = 0; r < 4; ++r) {
        const int m = mbase + r;
        float g = acc[i][j][r] + bvs;
        if constexpr (MODE == 5) {
          const int b = m >> 11, t = m & 2047;
          if (col < 768) {
            const int head = col >> 6, d = col & 63;
            ((u16*)C0)[(((size_t)(b * Hh + head) * Tt + t) << 6) + d] = f2b(g);
          } else if (col < 1536) {
            const int c = col - 768, head = c >> 6, d = c & 63;
            ((u16*)C1)[(((size_t)(b * Hh + head) * Tt + t) << 6) + d] = f2b(g);
          } else {
            const int c = col - 1536, head = c >> 6, d = c & 63;
            ((u16*)C2)[(((size_t)(b * Hh + head) * Hd + d) << 11) + t] = f2b(g);
          }
        } else if constexpr (MODE == 2) {
          g += add[(size_t)m * Dd + col];
          ((float*)C0)[(size_t)m * Dd + col] = g;
          ((u16*)C1)[(size_t)m * Dd + col] = f2b(g);
        } else if constexpr (MODE == 3) {
          ((u16*)C0)[(size_t)m * N + col] = f2b(gelu_exact(g));
        } else {
          g += add[(size_t)m * Dd + col];
          ((float*)C0)[(size_t)m * Dd + col] = g;
        }
      }
    }
  }
}

// ---------------------------------------------------------------------------
// Fused attention v2: all MFMA fragments (K, Q, V) loaded DIRECTLY from
// global (16B contiguous per lane; L1/L2-served).  Q fragments register-
// resident for all tiles.  LDS = Ps (32 KB) only.  Pass 1 barrier-free.
// S^T = mfma(K, Q): lane holds col q = wv*32+j*16+(lane&15),
// rows kv = i*16+(lane>>4)*4+r  -> softmax over kv = in-thread + xor16/32.
// ---------------------------------------------------------------------------
__global__ __launch_bounds__(256) void attn_fused(
    const u16* __restrict__ qb, const u16* __restrict__ kb,
    const u16* __restrict__ vtb, const float* __restrict__ maskf,
    float* __restrict__ attn, u16* __restrict__ ctxb) {
  const int bh = blockIdx.y;
  const int b = bh / Hh;
  const int q0 = blockIdx.x * 128;
  const u16* Qg = qb + (size_t)bh * Tt * Hd;
  const u16* Kg = kb + (size_t)bh * Tt * Hd;
  const u16* Vg = vtb + (size_t)bh * Hd * Tt;  // [64][2048]
  float* attng = attn + (size_t)bh * Tt * Tt;
  u16* ctxg = ctxb + (size_t)bh * Tt * Hd;
  const float* mfp = maskf + b * Tt;

  __shared__ __align__(16) u16 Ps[128 * 128];

  const int tid = threadIdx.x, lane = tid & 63, wv = tid >> 6;
  const int lc = lane & 15, lg = lane >> 4;

  // Q fragments once, register-resident (B-operand: col=lc -> q row, k=lg*8)
  short8 qf[2][2];
#pragma unroll
  for (int ks = 0; ks < 2; ++ks)
#pragma unroll
    for (int j = 0; j < 2; ++j)
      qf[ks][j] = *(const short8*)&Qg[(size_t)(q0 + wv * 32 + j * 16 + lc) * Hd +
                                      ks * 32 + lg * 8];

  float m[2] = {-1e30f, -1e30f}, l[2] = {0.f, 0.f};

  // ---------------- pass 1: running m, l (no barriers) ----------------
  for (int t = 0; t < 16; ++t) {
    const int kv0 = t * 128;
    f32x4 s[8][2] = {};
#pragma unroll
    for (int ks = 0; ks < 2; ++ks) {
      short8 af[8];
#pragma unroll
      for (int i = 0; i < 8; ++i)
        af[i] = *(const short8*)&Kg[(size_t)(kv0 + i * 16 + lc) * Hd + ks * 32 +
                                    lg * 8];
#pragma unroll
      for (int i = 0; i < 8; ++i)
#pragma unroll
        for (int j = 0; j < 2; ++j)
          s[i][j] = __builtin_amdgcn_mfma_f32_16x16x32_bf16(af[i], qf[ks][j],
                                                            s[i][j], 0, 0, 0);
    }
#pragma unroll
    for (int i = 0; i < 8; ++i) {
      const float4 mm = *(const float4*)&mfp[kv0 + i * 16 + lg * 4];
#pragma unroll
      for (int j = 0; j < 2; ++j) {
        s[i][j][0] = s[i][j][0] * 0.125f + mm.x;
        s[i][j][1] = s[i][j][1] * 0.125f + mm.y;
        s[i][j][2] = s[i][j][2] * 0.125f + mm.z;
        s[i][j][3] = s[i][j][3] * 0.125f + mm.w;
      }
    }
#pragma unroll
    for (int j = 0; j < 2; ++j) {
      float tm = -1e30f;
#pragma unroll
      for (int i = 0; i < 8; ++i)
#pragma unroll
        for (int r = 0; r < 4; ++r) tm = fmaxf(tm, s[i][j][r]);
      tm = fmaxf(tm, __shfl_xor(tm, 16));
      tm = fmaxf(tm, __shfl_xor(tm, 32));
      const float mn = fmaxf(m[j], tm);
      float ts = 0.f;
#pragma unroll
      for (int i = 0; i < 8; ++i)
#pragma unroll
        for (int r = 0; r < 4; ++r) ts += __expf(s[i][j][r] - mn);
      ts += __shfl_xor(ts, 16);
      ts += __shfl_xor(ts, 32);
      l[j] = l[j] * __expf(m[j] - mn) + ts;
      m[j] = mn;
    }
  }

  const float linv[2] = {1.f / l[0], 1.f / l[1]};
  f32x4 cacc[2][4] = {};

  // ---------------- pass 2: P write + ctx ----------------
  for (int t = 0; t < 16; ++t) {
    const int kv0 = t * 128;
    f32x4 s[8][2] = {};
#pragma unroll
    for (int ks = 0; ks < 2; ++ks) {
      short8 af[8];
#pragma unroll
      for (int i = 0; i < 8; ++i)
        af[i] = *(const short8*)&Kg[(size_t)(kv0 + i * 16 + lc) * Hd + ks * 32 +
                                    lg * 8];
#pragma unroll
      for (int i = 0; i < 8; ++i)
#pragma unroll
        for (int j = 0; j < 2; ++j)
          s[i][j] = __builtin_amdgcn_mfma_f32_16x16x32_bf16(af[i], qf[ks][j],
                                                            s[i][j], 0, 0, 0);
    }
#pragma unroll
    for (int j = 0; j < 2; ++j) {
      const int ql = wv * 32 + j * 16 + lc;
#pragma unroll
      for (int i = 0; i < 8; ++i) {
        const float4 mm = *(const float4*)&mfp[kv0 + i * 16 + lg * 4];
        const float mmv[4] = {mm.x, mm.y, mm.z, mm.w};
        float pv[4];
        u16 pb[4];
#pragma unroll
        for (int r = 0; r < 4; ++r) {
          const float v = s[i][j][r] * 0.125f + mmv[r];
          const float p = __expf(v - m[j]) * linv[j];
          pv[r] = p;
          pb[r] = f2b(p);
        }
        *(float4*)&attng[(size_t)(q0 + ql) * Tt + kv0 + i * 16 + lg * 4] =
            make_float4(pv[0], pv[1], pv[2], pv[3]);
        const int chunk = i * 2 + (lg >> 1);
        const int ph = chunk ^ (ql & 7);
        *(uint2*)&Ps[ql * 128 + ph * 8 + (lg & 1) * 4] = *(uint2*)pb;
      }
    }
    __syncthreads();

    // ctx += P @ V-tile  (V fragments straight from global V^T)
#pragma unroll
    for (int ks = 0; ks < 4; ++ks) {
      short8 pa[2], vb2[4];
#pragma unroll
      for (int i2 = 0; i2 < 2; ++i2) {
        const int qr = wv * 32 + i2 * 16 + lc;
        const int ph = (ks * 4 + lg) ^ (qr & 7);
        pa[i2] = *(const short8*)&Ps[qr * 128 + ph * 8];
      }
#pragma unroll
      for (int j2 = 0; j2 < 4; ++j2)
        vb2[j2] = *(const short8*)&Vg[(size_t)(j2 * 16 + lc) * Tt + kv0 +
                                      ks * 32 + lg * 8];
#pragma unroll
      for (int i2 = 0; i2 < 2; ++i2)
#pragma unroll
        for (int j2 = 0; j2 < 4; ++j2)
          cacc[i2][j2] = __builtin_amdgcn_mfma_f32_16x16x32_bf16(
              pa[i2], vb2[j2], cacc[i2][j2], 0, 0, 0);
    }
    __syncthreads();
  }

  // ctx epilogue: bf16 split-head
#pragma unroll
  for (int i2 = 0; i2 < 2; ++i2)
#pragma unroll
    for (int j2 = 0; j2 < 4; ++j2)
#pragma unroll
      for (int r = 0; r < 4; ++r) {
        const int q = q0 + wv * 32 + i2 * 16 + lg * 4 + r;
        const int d = j2 * 16 + lc;
        ctxg[(size_t)q * Hd + d] = f2b(cacc[i2][j2][r]);
      }
}

// ---------------------------------------------------------------------------
extern "C" void kernel_launch(void* const* d_in, const int* in_sizes, int n_in,
                              void* d_out, int out_size, void* d_ws,
                              size_t ws_size, hipStream_t stream) {
  const float* x = (const float*)d_in[0];
  const int* mask = (const int*)d_in[1];
  const float* Wq = (const float*)d_in[2];
  const float* bq = (const float*)d_in[3];
  const float* Wk = (const float*)d_in[4];
  const float* bk = (const float*)d_in[5];
  const float* Wv = (const float*)d_in[6];
  const float* bv = (const float*)d_in[7];
  const float* Wo = (const float*)d_in[8];
  const float* bo = (const float*)d_in[9];
  const float* W1 = (const float*)d_in[10];
  const float* b1 = (const float*)d_in[11];
  const float* W2 = (const float*)d_in[12];
  const float* b2 = (const float*)d_in[13];

  float* out = (float*)d_out;
  float* attn = out + (size_t)BT * Dd;

  char* w = (char*)d_ws;
  u16* xb = (u16*)w;      w += (size_t)BT * Dd * 2;
  u16* wqkvT = (u16*)w;   w += (size_t)Dd * 2304 * 2;
  u16* woT = (u16*)w;     w += (size_t)Dd * Dd * 2;
  u16* w1T = (u16*)w;     w += (size_t)Dd * Df * 2;
  u16* w2T = (u16*)w;     w += (size_t)Df * Dd * 2;
  float* biasc = (float*)w; w += 2304 * 4;
  float* maskf = (float*)w; w += (size_t)BT * 4;
  u16* qb = (u16*)w;      w += (size_t)BT * Dd * 2;
  u16* kb = (u16*)w;      w += (size_t)BT * Dd * 2;
  u16* vtb = (u16*)w;     w += (size_t)BT * Dd * 2;
  u16* ctxb = (u16*)w;    w += (size_t)BT * Dd * 2;
  u16* ff1b = (u16*)w;    w += (size_t)BT * Df * 2;
  float* h = (float*)qb;  // overlays qb+kb (dead after attn_fused)
  u16* hb = vtb;          // overlays vtb (dead after attn_fused)

  dim3 blk(256);

  // all prep in one launch
  prep_all<<<dim3(10025), blk, 0, stream>>>(x, Wq, Wk, Wv, Wo, W1, W2, bq, bk,
                                            bv, mask, xb, wqkvT, woT, w1T, w2T,
                                            biasc, maskf);

  // fused QKV projection (N = 2304)
  mgemm<5><<<dim3(18, 64), blk, 0, stream>>>(xb, wqkvT, biasc, nullptr, qb, kb,
                                             vtb, Dd, 2304);

  // fused attention: attn (written once) + ctx
  attn_fused<<<dim3(16, 48), blk, 0, stream>>>(qb, kb, vtb, maskf, attn, ctxb);

  // h = x + ctx@Wo + bo   (fp32 + bf16)
  mgemm<2><<<dim3(6, 64), blk, 0, stream>>>(ctxb, woT, bo, x, h, hb, nullptr,
                                            Dd, Dd);

  // ff1 = gelu(h@W1 + b1) bf16
  mgemm<3><<<dim3(24, 64), blk, 0, stream>>>(hb, w1T, b1, nullptr, ff1b,
                                             nullptr, nullptr, Dd, Df);

  // out = h + ff1@W2 + b2
  mgemm<4><<<dim3(6, 64), blk, 0, stream>>>(ff1b, w2T, b2, h, out, nullptr,
                                            nullptr, Df, Dd);
}

// Round 5
// 638.162 us; speedup vs baseline: 1.3776x; 1.3776x over previous
//
#include <hip/hip_runtime.h>
#include <hip/hip_bf16.h>
#include <math.h>

typedef unsigned short u16;
typedef __attribute__((ext_vector_type(8))) short short8;
typedef __attribute__((ext_vector_type(4))) float f32x4;

constexpr int Bc = 4, Tt = 2048, Dd = 768, Hh = 12, Hd = 64, Df = 3072;
constexpr int BT = Bc * Tt;  // 8192

__device__ __forceinline__ u16 f2b(float x) {
  __hip_bfloat16 h = __float2bfloat16(x);
  return *reinterpret_cast<u16*>(&h);
}
__device__ __forceinline__ float gelu_exact(float g) {
  return 0.5f * g * (1.0f + erff(g * 0.70710678118654752440f));
}
__device__ __forceinline__ void gload16(const void* g, void* l) {
  __builtin_amdgcn_global_load_lds(
      (const __attribute__((address_space(1))) unsigned int*)g,
      (__attribute__((address_space(3))) unsigned int*)l, 16, 0, 0);
}

// ---------------------------------------------------------------------------
// 32x32 transpose tile: in [R][C] fp32 -> out [C][R] bf16
// ---------------------------------------------------------------------------
__device__ __forceinline__ void tr_tile(const float* __restrict__ in,
                                        u16* __restrict__ out, int R, int C,
                                        int bx, int by, float* sh) {
  const int tx = threadIdx.x & 31, ty = threadIdx.x >> 5;
  const int r0 = by * 32, c0 = bx * 32;
#pragma unroll
  for (int i = 0; i < 4; ++i)
    sh[(ty + i * 8) * 33 + tx] = in[(size_t)(r0 + ty + i * 8) * C + c0 + tx];
  __syncthreads();
#pragma unroll
  for (int i = 0; i < 4; ++i)
    out[(size_t)(c0 + ty + i * 8) * R + r0 + tx] = f2b(sh[tx * 33 + ty + i * 8]);
}

// ---------------------------------------------------------------------------
// One fused prep kernel, dispatched by block range.
// ---------------------------------------------------------------------------
__global__ __launch_bounds__(256) void prep_all(
    const float* __restrict__ x, const float* __restrict__ Wq,
    const float* __restrict__ Wk, const float* __restrict__ Wv,
    const float* __restrict__ Wo, const float* __restrict__ W1,
    const float* __restrict__ W2, const float* __restrict__ bq,
    const float* __restrict__ bk, const float* __restrict__ bv,
    const int* __restrict__ mask, u16* __restrict__ xb,
    u16* __restrict__ wqkvT, u16* __restrict__ woT, u16* __restrict__ w1T,
    u16* __restrict__ w2T, float* __restrict__ biasc,
    float* __restrict__ maskf) {
  __shared__ float sh[32 * 33];
  const int s = blockIdx.x;
  if (s < 3072) {
    int i = (s * 256 + threadIdx.x) * 8;
    float4 a = *(const float4*)&x[i];
    float4 b = *(const float4*)&x[i + 4];
    u16 t[8] = {f2b(a.x), f2b(a.y), f2b(a.z), f2b(a.w),
                f2b(b.x), f2b(b.y), f2b(b.z), f2b(b.w)};
    *(uint4*)&xb[i] = *(uint4*)t;
  } else if (s < 3648) {
    int u = s - 3072; tr_tile(Wq, wqkvT, Dd, Dd, u % 24, u / 24, sh);
  } else if (s < 4224) {
    int u = s - 3648; tr_tile(Wk, wqkvT + 768 * Dd, Dd, Dd, u % 24, u / 24, sh);
  } else if (s < 4800) {
    int u = s - 4224; tr_tile(Wv, wqkvT + 1536 * Dd, Dd, Dd, u % 24, u / 24, sh);
  } else if (s < 5376) {
    int u = s - 4800; tr_tile(Wo, woT, Dd, Dd, u % 24, u / 24, sh);
  } else if (s < 7680) {
    int u = s - 5376; tr_tile(W1, w1T, Dd, Df, u % 96, u / 96, sh);
  } else if (s < 9984) {
    int u = s - 7680; tr_tile(W2, w2T, Df, Dd, u % 24, u / 24, sh);
  } else {
    int i = (s - 9984) * 256 + threadIdx.x;
    if (i < 2304)
      biasc[i] = (i < 768) ? bq[i] : (i < 1536) ? bk[i - 768] : bv[i - 1536];
    int j = i - 2304;
    if (j >= 0 && j < BT) maskf[j] = mask[j] ? 0.f : -1e30f;
  }
}

// ---------------------------------------------------------------------------
// bf16 MFMA NT GEMM, 128x128 tile, BK=32, 4 waves.
// MODE 5: QKV fused (N=2304): Q split-head | K split-head | V^T [B,H,64,T]
// MODE 2: C0 fp32 h = add + acc + bias; C1 bf16 h  (Wo, A gathered split-head)
// MODE 3: C0 bf16 gelu(acc + bias)                 (FF1)
// MODE 4: C0 fp32 add + acc + bias                 (FF2)
// ---------------------------------------------------------------------------
template <int MODE>
__global__ __launch_bounds__(256) void mgemm(
    const u16* __restrict__ A, const u16* __restrict__ Bt,
    const float* __restrict__ bias, const float* __restrict__ add,
    void* __restrict__ C0, void* __restrict__ C1, void* __restrict__ C2,
    int K, int N) {
  __shared__ __align__(16) u16 As[128 * 32];
  __shared__ __align__(16) u16 Bs[128 * 32];
  const int tid = threadIdx.x;
  const int lane = tid & 63, wv = tid >> 6;
  const int m0 = blockIdx.y * 128, n0 = blockIdx.x * 128;
  const int wm = (wv >> 1) * 64, wn = (wv & 1) * 64;

  f32x4 acc[4][4] = {};

  for (int k0 = 0; k0 < K; k0 += 32) {
#pragma unroll
    for (int i = 0; i < 2; ++i) {
      const int idx = i * 256 + tid;
      const int row = idx >> 2;
      const int kc = (idx & 3) * 8;
      const u16* ga;
      if constexpr (MODE == 2) {
        const int m = m0 + row, b = m >> 11, t = m & 2047;
        const int kk = k0 + kc, head = kk >> 6, d = kk & 63;
        ga = &A[(((size_t)(b * Hh + head) * Tt + t) << 6) + d];
      } else {
        ga = &A[(size_t)(m0 + row) * K + k0 + kc];
      }
      gload16(ga, &As[idx * 8]);
      gload16(&Bt[(size_t)(n0 + row) * K + k0 + kc], &Bs[idx * 8]);
    }
    __syncthreads();
    short8 af[4], bfr[4];
#pragma unroll
    for (int i = 0; i < 4; ++i) {
      af[i] = *reinterpret_cast<const short8*>(
          &As[(wm + i * 16 + (lane & 15)) * 32 + (lane >> 4) * 8]);
      bfr[i] = *reinterpret_cast<const short8*>(
          &Bs[(wn + i * 16 + (lane & 15)) * 32 + (lane >> 4) * 8]);
    }
#pragma unroll
    for (int i = 0; i < 4; ++i)
#pragma unroll
      for (int j = 0; j < 4; ++j)
        acc[i][j] = __builtin_amdgcn_mfma_f32_16x16x32_bf16(af[i], bfr[j],
                                                            acc[i][j], 0, 0, 0);
    __syncthreads();
  }

  const int lr = (lane >> 4) * 4, lc = lane & 15;
#pragma unroll
  for (int i = 0; i < 4; ++i) {
    const int mbase = m0 + wm + i * 16 + lr;
#pragma unroll
    for (int j = 0; j < 4; ++j) {
      const int col = n0 + wn + j * 16 + lc;
      const float bvs = bias[col];
#pragma unroll
      for (int r = 0; r < 4; ++r) {
        const int m = mbase + r;
        float g = acc[i][j][r] + bvs;
        if constexpr (MODE == 5) {
          const int b = m >> 11, t = m & 2047;
          if (col < 768) {
            const int head = col >> 6, d = col & 63;
            ((u16*)C0)[(((size_t)(b * Hh + head) * Tt + t) << 6) + d] = f2b(g);
          } else if (col < 1536) {
            const int c = col - 768, head = c >> 6, d = c & 63;
            ((u16*)C1)[(((size_t)(b * Hh + head) * Tt + t) << 6) + d] = f2b(g);
          } else {
            const int c = col - 1536, head = c >> 6, d = c & 63;
            ((u16*)C2)[(((size_t)(b * Hh + head) * Hd + d) << 11) + t] = f2b(g);
          }
        } else if constexpr (MODE == 2) {
          g += add[(size_t)m * Dd + col];
          ((float*)C0)[(size_t)m * Dd + col] = g;
          ((u16*)C1)[(size_t)m * Dd + col] = f2b(g);
        } else if constexpr (MODE == 3) {
          ((u16*)C0)[(size_t)m * N + col] = f2b(gelu_exact(g));
        } else {
          g += add[(size_t)m * Dd + col];
          ((float*)C0)[(size_t)m * Dd + col] = g;
        }
      }
    }
  }
}

// ---------------------------------------------------------------------------
// Fused attention v3: K/V staged via global_load_lds (coalesced, swizzled
// source); Q fragments register-resident; LDS = Ks16K+Vs16K+Ps32K = 64KB
// -> 2 blocks/CU.  No-max softmax (scores bounded; exp safe in fp32):
// l = sum exp(s), p = exp(s)/l — identical math to reference softmax.
// S^T = mfma(K, Q): lane holds col q, rows kv -> row-sum = in-thread
// + xor16/32 shuffles.  attn written exactly once.
// ---------------------------------------------------------------------------
__global__ __launch_bounds__(256) void attn_fused(
    const u16* __restrict__ qb, const u16* __restrict__ kb,
    const u16* __restrict__ vtb, const float* __restrict__ maskf,
    float* __restrict__ attn, u16* __restrict__ ctxb) {
  const int bh = blockIdx.y;
  const int b = bh / Hh;
  const int q0 = blockIdx.x * 128;
  const u16* Qg = qb + (size_t)bh * Tt * Hd;
  const u16* Kg = kb + (size_t)bh * Tt * Hd;
  const u16* Vg = vtb + (size_t)bh * Hd * Tt;  // [64][2048]
  float* attng = attn + (size_t)bh * Tt * Tt;
  u16* ctxg = ctxb + (size_t)bh * Tt * Hd;
  const float* mfp = maskf + b * Tt;

  __shared__ __align__(16) u16 Ks[128 * 64];
  __shared__ __align__(16) u16 Vs[64 * 128];
  __shared__ __align__(16) u16 Ps[128 * 128];

  const int tid = threadIdx.x, lane = tid & 63, wv = tid >> 6;
  const int lc = lane & 15, lg = lane >> 4;

  // Q fragments once, register-resident (one-time gather; B-operand)
  short8 qf[2][2];
#pragma unroll
  for (int ks = 0; ks < 2; ++ks)
#pragma unroll
    for (int j = 0; j < 2; ++j)
      qf[ks][j] = *(const short8*)&Qg[(size_t)(q0 + wv * 32 + j * 16 + lc) * Hd +
                                      ks * 32 + lg * 8];

  float l[2] = {0.f, 0.f};

  // ---------------- pass 1: row sums l ----------------
  for (int t = 0; t < 16; ++t) {
    const int kv0 = t * 128;
#pragma unroll
    for (int w = 0; w < 4; ++w) {
      int p = w * 256 + tid;
      int row = p >> 3, kc8 = (p & 7) ^ (row & 7);
      gload16(Kg + (size_t)(kv0 + row) * Hd + kc8 * 8, &Ks[p * 8]);
    }
    __syncthreads();

    f32x4 s[8][2] = {};
#pragma unroll
    for (int ks = 0; ks < 2; ++ks) {
      short8 af[8];
#pragma unroll
      for (int i = 0; i < 8; ++i) {
        const int ph = (ks * 4 + lg) ^ (lc & 7);
        af[i] = *(const short8*)&Ks[(i * 16 + lc) * 64 + ph * 8];
      }
#pragma unroll
      for (int i = 0; i < 8; ++i)
#pragma unroll
        for (int j = 0; j < 2; ++j)
          s[i][j] = __builtin_amdgcn_mfma_f32_16x16x32_bf16(af[i], qf[ks][j],
                                                            s[i][j], 0, 0, 0);
    }
#pragma unroll
    for (int j = 0; j < 2; ++j) {
      float ts = 0.f;
#pragma unroll
      for (int i = 0; i < 8; ++i) {
        const float4 mm = *(const float4*)&mfp[kv0 + i * 16 + lg * 4];
        ts += __expf(s[i][j][0] * 0.125f + mm.x);
        ts += __expf(s[i][j][1] * 0.125f + mm.y);
        ts += __expf(s[i][j][2] * 0.125f + mm.z);
        ts += __expf(s[i][j][3] * 0.125f + mm.w);
      }
      ts += __shfl_xor(ts, 16);
      ts += __shfl_xor(ts, 32);
      l[j] += ts;
    }
    __syncthreads();
  }

  const float linv[2] = {1.f / l[0], 1.f / l[1]};
  f32x4 cacc[2][4] = {};

  // ---------------- pass 2: P write + ctx ----------------
  for (int t = 0; t < 16; ++t) {
    const int kv0 = t * 128;
#pragma unroll
    for (int w = 0; w < 4; ++w) {
      int p = w * 256 + tid;
      int row = p >> 3, kc8 = (p & 7) ^ (row & 7);
      gload16(Kg + (size_t)(kv0 + row) * Hd + kc8 * 8, &Ks[p * 8]);
    }
#pragma unroll
    for (int w = 0; w < 4; ++w) {
      int p = w * 256 + tid;
      int d = p >> 4, pc = (p & 15) ^ (d & 7);
      gload16(Vg + (size_t)d * Tt + kv0 + pc * 8, &Vs[p * 8]);
    }
    __syncthreads();

    f32x4 s[8][2] = {};
#pragma unroll
    for (int ks = 0; ks < 2; ++ks) {
      short8 af[8];
#pragma unroll
      for (int i = 0; i < 8; ++i) {
        const int ph = (ks * 4 + lg) ^ (lc & 7);
        af[i] = *(const short8*)&Ks[(i * 16 + lc) * 64 + ph * 8];
      }
#pragma unroll
      for (int i = 0; i < 8; ++i)
#pragma unroll
        for (int j = 0; j < 2; ++j)
          s[i][j] = __builtin_amdgcn_mfma_f32_16x16x32_bf16(af[i], qf[ks][j],
                                                            s[i][j], 0, 0, 0);
    }
#pragma unroll
    for (int j = 0; j < 2; ++j) {
      const int ql = wv * 32 + j * 16 + lc;
#pragma unroll
      for (int i = 0; i < 8; ++i) {
        const float4 mm = *(const float4*)&mfp[kv0 + i * 16 + lg * 4];
        const float mmv[4] = {mm.x, mm.y, mm.z, mm.w};
        float pv[4];
        u16 pb[4];
#pragma unroll
        for (int r = 0; r < 4; ++r) {
          const float p = __expf(s[i][j][r] * 0.125f + mmv[r]) * linv[j];
          pv[r] = p;
          pb[r] = f2b(p);
        }
        *(float4*)&attng[(size_t)(q0 + ql) * Tt + kv0 + i * 16 + lg * 4] =
            make_float4(pv[0], pv[1], pv[2], pv[3]);
        const int chunk = i * 2 + (lg >> 1);
        const int ph = chunk ^ (ql & 7);
        *(uint2*)&Ps[ql * 128 + ph * 8 + (lg & 1) * 4] = *(uint2*)pb;
      }
    }
    __syncthreads();

    // ctx += P @ V-tile
#pragma unroll
    for (int ks = 0; ks < 4; ++ks) {
      short8 pa[2], vb2[4];
#pragma unroll
      for (int i2 = 0; i2 < 2; ++i2) {
        const int qr = wv * 32 + i2 * 16 + lc;
        const int ph = (ks * 4 + lg) ^ (qr & 7);
        pa[i2] = *(const short8*)&Ps[qr * 128 + ph * 8];
      }
#pragma unroll
      for (int j2 = 0; j2 < 4; ++j2) {
        const int d = j2 * 16 + lc;
        const int ph = (ks * 4 + lg) ^ (d & 7);
        vb2[j2] = *(const short8*)&Vs[d * 128 + ph * 8];
      }
#pragma unroll
      for (int i2 = 0; i2 < 2; ++i2)
#pragma unroll
        for (int j2 = 0; j2 < 4; ++j2)
          cacc[i2][j2] = __builtin_amdgcn_mfma_f32_16x16x32_bf16(
              pa[i2], vb2[j2], cacc[i2][j2], 0, 0, 0);
    }
    __syncthreads();
  }

  // ctx epilogue: bf16 split-head
#pragma unroll
  for (int i2 = 0; i2 < 2; ++i2)
#pragma unroll
    for (int j2 = 0; j2 < 4; ++j2)
#pragma unroll
      for (int r = 0; r < 4; ++r) {
        const int q = q0 + wv * 32 + i2 * 16 + lg * 4 + r;
        const int d = j2 * 16 + lc;
        ctxg[(size_t)q * Hd + d] = f2b(cacc[i2][j2][r]);
      }
}

// ---------------------------------------------------------------------------
extern "C" void kernel_launch(void* const* d_in, const int* in_sizes, int n_in,
                              void* d_out, int out_size, void* d_ws,
                              size_t ws_size, hipStream_t stream) {
  const float* x = (const float*)d_in[0];
  const int* mask = (const int*)d_in[1];
  const float* Wq = (const float*)d_in[2];
  const float* bq = (const float*)d_in[3];
  const float* Wk = (const float*)d_in[4];
  const float* bk = (const float*)d_in[5];
  const float* Wv = (const float*)d_in[6];
  const float* bv = (const float*)d_in[7];
  const float* Wo = (const float*)d_in[8];
  const float* bo = (const float*)d_in[9];
  const float* W1 = (const float*)d_in[10];
  const float* b1 = (const float*)d_in[11];
  const float* W2 = (const float*)d_in[12];
  const float* b2 = (const float*)d_in[13];

  float* out = (float*)d_out;
  float* attn = out + (size_t)BT * Dd;

  char* w = (char*)d_ws;
  u16* xb = (u16*)w;      w += (size_t)BT * Dd * 2;
  u16* wqkvT = (u16*)w;   w += (size_t)Dd * 2304 * 2;
  u16* woT = (u16*)w;     w += (size_t)Dd * Dd * 2;
  u16* w1T = (u16*)w;     w += (size_t)Dd * Df * 2;
  u16* w2T = (u16*)w;     w += (size_t)Df * Dd * 2;
  float* biasc = (float*)w; w += 2304 * 4;
  float* maskf = (float*)w; w += (size_t)BT * 4;
  u16* qb = (u16*)w;      w += (size_t)BT * Dd * 2;
  u16* kb = (u16*)w;      w += (size_t)BT * Dd * 2;
  u16* vtb = (u16*)w;     w += (size_t)BT * Dd * 2;
  u16* ctxb = (u16*)w;    w += (size_t)BT * Dd * 2;
  u16* ff1b = (u16*)w;    w += (size_t)BT * Df * 2;
  float* h = (float*)qb;  // overlays qb+kb (dead after attn_fused)
  u16* hb = vtb;          // overlays vtb (dead after attn_fused)

  dim3 blk(256);

  // all prep in one launch
  prep_all<<<dim3(10025), blk, 0, stream>>>(x, Wq, Wk, Wv, Wo, W1, W2, bq, bk,
                                            bv, mask, xb, wqkvT, woT, w1T, w2T,
                                            biasc, maskf);

  // fused QKV projection (N = 2304)
  mgemm<5><<<dim3(18, 64), blk, 0, stream>>>(xb, wqkvT, biasc, nullptr, qb, kb,
                                             vtb, Dd, 2304);

  // fused attention: attn (written once) + ctx
  attn_fused<<<dim3(16, 48), blk, 0, stream>>>(qb, kb, vtb, maskf, attn, ctxb);

  // h = x + ctx@Wo + bo   (fp32 + bf16)
  mgemm<2><<<dim3(6, 64), blk, 0, stream>>>(ctxb, woT, bo, x, h, hb, nullptr,
                                            Dd, Dd);

  // ff1 = gelu(h@W1 + b1) bf16
  mgemm<3><<<dim3(24, 64), blk, 0, stream>>>(hb, w1T, b1, nullptr, ff1b,
                                             nullptr, nullptr, Dd, Df);

  // out = h + ff1@W2 + b2
  mgemm<4><<<dim3(6, 64), blk, 0, stream>>>(ff1b, w2T, b2, h, out, nullptr,
                                            nullptr, Df, Dd);
}

// Round 6
// 636.419 us; speedup vs baseline: 1.3814x; 1.0027x over previous
//
#include <hip/hip_runtime.h>
#include <hip/hip_bf16.h>
#include <math.h>

typedef unsigned short u16;
typedef __attribute__((ext_vector_type(8))) short short8;
typedef __attribute__((ext_vector_type(4))) float f32x4;

constexpr int Bc = 4, Tt = 2048, Dd = 768, Hh = 12, Hd = 64, Df = 3072;
constexpr int BT = Bc * Tt;  // 8192

__device__ __forceinline__ u16 f2b(float x) {
  __hip_bfloat16 h = __float2bfloat16(x);
  return *reinterpret_cast<u16*>(&h);
}
__device__ __forceinline__ float gelu_exact(float g) {
  return 0.5f * g * (1.0f + erff(g * 0.70710678118654752440f));
}
__device__ __forceinline__ void gload16(const void* g, void* l) {
  __builtin_amdgcn_global_load_lds(
      (const __attribute__((address_space(1))) unsigned int*)g,
      (__attribute__((address_space(3))) unsigned int*)l, 16, 0, 0);
}

// ---------------------------------------------------------------------------
// 32x32 transpose tile: in [R][C] fp32 -> out [C][R] bf16
// ---------------------------------------------------------------------------
__device__ __forceinline__ void tr_tile(const float* __restrict__ in,
                                        u16* __restrict__ out, int R, int C,
                                        int bx, int by, float* sh) {
  const int tx = threadIdx.x & 31, ty = threadIdx.x >> 5;
  const int r0 = by * 32, c0 = bx * 32;
#pragma unroll
  for (int i = 0; i < 4; ++i)
    sh[(ty + i * 8) * 33 + tx] = in[(size_t)(r0 + ty + i * 8) * C + c0 + tx];
  __syncthreads();
#pragma unroll
  for (int i = 0; i < 4; ++i)
    out[(size_t)(c0 + ty + i * 8) * R + r0 + tx] = f2b(sh[tx * 33 + ty + i * 8]);
}

// ---------------------------------------------------------------------------
// One fused prep kernel, dispatched by block range.
// ---------------------------------------------------------------------------
__global__ __launch_bounds__(256) void prep_all(
    const float* __restrict__ x, const float* __restrict__ Wq,
    const float* __restrict__ Wk, const float* __restrict__ Wv,
    const float* __restrict__ Wo, const float* __restrict__ W1,
    const float* __restrict__ W2, const float* __restrict__ bq,
    const float* __restrict__ bk, const float* __restrict__ bv,
    const int* __restrict__ mask, u16* __restrict__ xb,
    u16* __restrict__ wqkvT, u16* __restrict__ woT, u16* __restrict__ w1T,
    u16* __restrict__ w2T, float* __restrict__ biasc,
    unsigned int* __restrict__ mwords) {
  __shared__ float sh[32 * 33];
  const int s = blockIdx.x;
  if (s < 3072) {
    int i = (s * 256 + threadIdx.x) * 8;
    float4 a = *(const float4*)&x[i];
    float4 b = *(const float4*)&x[i + 4];
    u16 t[8] = {f2b(a.x), f2b(a.y), f2b(a.z), f2b(a.w),
                f2b(b.x), f2b(b.y), f2b(b.z), f2b(b.w)};
    *(uint4*)&xb[i] = *(uint4*)t;
  } else if (s < 3648) {
    int u = s - 3072; tr_tile(Wq, wqkvT, Dd, Dd, u % 24, u / 24, sh);
  } else if (s < 4224) {
    int u = s - 3648; tr_tile(Wk, wqkvT + 768 * Dd, Dd, Dd, u % 24, u / 24, sh);
  } else if (s < 4800) {
    int u = s - 4224; tr_tile(Wv, wqkvT + 1536 * Dd, Dd, Dd, u % 24, u / 24, sh);
  } else if (s < 5376) {
    int u = s - 4800; tr_tile(Wo, woT, Dd, Dd, u % 24, u / 24, sh);
  } else if (s < 7680) {
    int u = s - 5376; tr_tile(W1, w1T, Dd, Df, u % 96, u / 96, sh);
  } else if (s < 9984) {
    int u = s - 7680; tr_tile(W2, w2T, Df, Dd, u % 24, u / 24, sh);
  } else if (s < 9993) {
    int i = (s - 9984) * 256 + threadIdx.x;  // 0..2303
    biasc[i] = (i < 768) ? bq[i] : (i < 1536) ? bk[i - 768] : bv[i - 1536];
  } else {
    // pack mask bits: mwords[b*64 + w] bit j = mask[b*2048 + w*32 + j]
    const int id = threadIdx.x;  // 0..255
    const int b_ = id >> 6, kv0 = (id & 63) * 32;
    unsigned int wbits = 0u;
    for (int j = 0; j < 32; ++j)
      wbits |= (mask[b_ * Tt + kv0 + j] ? 1u : 0u) << j;
    mwords[id] = wbits;
  }
}

// ---------------------------------------------------------------------------
// bf16 MFMA NT GEMM, 128x128 tile, BK=32, 4 waves.
// MODE 5: QKV fused (N=2304): Q split-head | K split-head | V^T [B,H,64,T]
// MODE 2: C0 fp32 h = add + acc + bias; C1 bf16 h  (Wo, A gathered split-head)
// MODE 3: C0 bf16 gelu(acc + bias)                 (FF1)
// MODE 4: C0 fp32 add + acc + bias                 (FF2)
// ---------------------------------------------------------------------------
template <int MODE>
__global__ __launch_bounds__(256) void mgemm(
    const u16* __restrict__ A, const u16* __restrict__ Bt,
    const float* __restrict__ bias, const float* __restrict__ add,
    void* __restrict__ C0, void* __restrict__ C1, void* __restrict__ C2,
    int K, int N) {
  __shared__ __align__(16) u16 As[128 * 32];
  __shared__ __align__(16) u16 Bs[128 * 32];
  const int tid = threadIdx.x;
  const int lane = tid & 63, wv = tid >> 6;
  const int m0 = blockIdx.y * 128, n0 = blockIdx.x * 128;
  const int wm = (wv >> 1) * 64, wn = (wv & 1) * 64;

  f32x4 acc[4][4] = {};

  for (int k0 = 0; k0 < K; k0 += 32) {
#pragma unroll
    for (int i = 0; i < 2; ++i) {
      const int idx = i * 256 + tid;
      const int row = idx >> 2;
      const int kc = (idx & 3) * 8;
      const u16* ga;
      if constexpr (MODE == 2) {
        const int m = m0 + row, b = m >> 11, t = m & 2047;
        const int kk = k0 + kc, head = kk >> 6, d = kk & 63;
        ga = &A[(((size_t)(b * Hh + head) * Tt + t) << 6) + d];
      } else {
        ga = &A[(size_t)(m0 + row) * K + k0 + kc];
      }
      gload16(ga, &As[idx * 8]);
      gload16(&Bt[(size_t)(n0 + row) * K + k0 + kc], &Bs[idx * 8]);
    }
    __syncthreads();
    short8 af[4], bfr[4];
#pragma unroll
    for (int i = 0; i < 4; ++i) {
      af[i] = *reinterpret_cast<const short8*>(
          &As[(wm + i * 16 + (lane & 15)) * 32 + (lane >> 4) * 8]);
      bfr[i] = *reinterpret_cast<const short8*>(
          &Bs[(wn + i * 16 + (lane & 15)) * 32 + (lane >> 4) * 8]);
    }
#pragma unroll
    for (int i = 0; i < 4; ++i)
#pragma unroll
      for (int j = 0; j < 4; ++j)
        acc[i][j] = __builtin_amdgcn_mfma_f32_16x16x32_bf16(af[i], bfr[j],
                                                            acc[i][j], 0, 0, 0);
    __syncthreads();
  }

  const int lr = (lane >> 4) * 4, lc = lane & 15;
#pragma unroll
  for (int i = 0; i < 4; ++i) {
    const int mbase = m0 + wm + i * 16 + lr;
#pragma unroll
    for (int j = 0; j < 4; ++j) {
      const int col = n0 + wn + j * 16 + lc;
      const float bvs = bias[col];
#pragma unroll
      for (int r = 0; r < 4; ++r) {
        const int m = mbase + r;
        float g = acc[i][j][r] + bvs;
        if constexpr (MODE == 5) {
          const int b = m >> 11, t = m & 2047;
          if (col < 768) {
            const int head = col >> 6, d = col & 63;
            ((u16*)C0)[(((size_t)(b * Hh + head) * Tt + t) << 6) + d] = f2b(g);
          } else if (col < 1536) {
            const int c = col - 768, head = c >> 6, d = c & 63;
            ((u16*)C1)[(((size_t)(b * Hh + head) * Tt + t) << 6) + d] = f2b(g);
          } else {
            const int c = col - 1536, head = c >> 6, d = c & 63;
            ((u16*)C2)[(((size_t)(b * Hh + head) * Hd + d) << 11) + t] = f2b(g);
          }
        } else if constexpr (MODE == 2) {
          g += add[(size_t)m * Dd + col];
          ((float*)C0)[(size_t)m * Dd + col] = g;
          ((u16*)C1)[(size_t)m * Dd + col] = f2b(g);
        } else if constexpr (MODE == 3) {
          ((u16*)C0)[(size_t)m * N + col] = f2b(gelu_exact(g));
        } else {
          g += add[(size_t)m * Dd + col];
          ((float*)C0)[(size_t)m * Dd + col] = g;
        }
      }
    }
  }
}

// ---------------------------------------------------------------------------
// Fused attention v4: counted-vmcnt pipeline (stores never drained in-loop).
// 64 q-rows/block, 4 waves (16 q-rows each).  K/V double-buffered LDS,
// staged 1 tile ahead via global_load_lds; raw s_barrier + s_waitcnt vmcnt(N)
// where N counted so only staging loads are waited, attn stores float.
// Mask as packed bits (uniform s_load, lgkm queue): p = exp(s/8)*bit.
// LDS: Ks 2x16K + Vs 2x16K + Ps 16K = 80KB -> 2 blocks/CU.
// ---------------------------------------------------------------------------
__global__ __launch_bounds__(256) void attn_fused(
    const u16* __restrict__ qb, const u16* __restrict__ kb,
    const u16* __restrict__ vtb, const unsigned int* __restrict__ mwords,
    float* __restrict__ attn, u16* __restrict__ ctxb) {
  const int bh = blockIdx.y;
  const int b = bh / Hh;
  const int q0 = blockIdx.x * 64;
  const u16* Qg = qb + (size_t)bh * Tt * Hd;
  const u16* Kg = kb + (size_t)bh * Tt * Hd;
  const u16* Vg = vtb + (size_t)bh * Hd * Tt;  // [64][2048]
  float* attng = attn + (size_t)bh * Tt * Tt;
  u16* ctxg = ctxb + (size_t)bh * Tt * Hd;
  const unsigned int* mwp = mwords + b * 64;

  __shared__ __align__(16) u16 Ks[2][128 * 64];
  __shared__ __align__(16) u16 Vs[2][64 * 128];
  __shared__ __align__(16) u16 Ps[64 * 128];

  const int tid = threadIdx.x, lane = tid & 63, wv = tid >> 6;
  const int lc = lane & 15, lg = lane >> 4;
  const int ql = wv * 16 + lc;  // local q row owned as MFMA col

#define STAGE_K(t, bf)                                                       \
  {                                                                          \
    const int kv0_ = (t) * 128;                                              \
    _Pragma("unroll") for (int w_ = 0; w_ < 4; ++w_) {                       \
      const int p_ = w_ * 256 + tid;                                         \
      const int row_ = p_ >> 3, kc8_ = (p_ & 7) ^ (row_ & 7);                \
      gload16(Kg + (size_t)(kv0_ + row_) * Hd + kc8_ * 8, &Ks[bf][p_ * 8]);  \
    }                                                                        \
  }
#define STAGE_V(t, bf)                                                       \
  {                                                                          \
    const int kv0_ = (t) * 128;                                              \
    _Pragma("unroll") for (int w_ = 0; w_ < 4; ++w_) {                       \
      const int p_ = w_ * 256 + tid;                                         \
      const int d_ = p_ >> 4, pc_ = (p_ & 15) ^ (d_ & 7);                    \
      gload16(Vg + (size_t)d_ * Tt + kv0_ + pc_ * 8, &Vs[bf][p_ * 8]);       \
    }                                                                        \
  }
#define FENCE() asm volatile("" ::: "memory")

  // Q fragments once, register-resident (B-operand; one-time gather)
  short8 qf[2];
#pragma unroll
  for (int ks = 0; ks < 2; ++ks)
    qf[ks] = *(const short8*)&Qg[(size_t)(q0 + ql) * Hd + ks * 32 + lg * 8];

  float l = 0.f;

  // ---------------- pass 1: row sums l ----------------
  STAGE_K(0, 0);
  STAGE_K(1, 1);
  for (int t = 0; t < 16; ++t) {
    // queue: [K_t(4) | K_{t+1}(4)] -> wait K_t only
    asm volatile("s_waitcnt vmcnt(4)" ::: "memory");
    __builtin_amdgcn_s_barrier();
    FENCE();
    const int bf = t & 1;
    f32x4 s[8] = {};
#pragma unroll
    for (int ks = 0; ks < 2; ++ks) {
      const int ph = (ks * 4 + lg) ^ (lc & 7);
#pragma unroll
      for (int i = 0; i < 8; ++i) {
        const short8 af = *(const short8*)&Ks[bf][(i * 16 + lc) * 64 + ph * 8];
        s[i] = __builtin_amdgcn_mfma_f32_16x16x32_bf16(af, qf[ks], s[i], 0, 0, 0);
      }
    }
    const uint4 mw4 = *(const uint4*)&mwp[t * 4];
    const unsigned int mwa[4] = {mw4.x, mw4.y, mw4.z, mw4.w};
    float ts = 0.f;
#pragma unroll
    for (int i = 0; i < 8; ++i) {
      const unsigned int w = mwa[i >> 1];
#pragma unroll
      for (int r = 0; r < 4; ++r) {
        const float bit = (float)((w >> ((i & 1) * 16 + lg * 4 + r)) & 1u);
        ts += __expf(s[i][r] * 0.125f) * bit;
      }
    }
    ts += __shfl_xor(ts, 16);
    ts += __shfl_xor(ts, 32);
    l += ts;
    asm volatile("s_waitcnt lgkmcnt(0)" ::: "memory");
    __builtin_amdgcn_s_barrier();
    FENCE();
    STAGE_K((t + 2) & 15, bf);  // overwrite just-read buffer (wrap = same data)
  }

  const float linv = 1.f / l;
  f32x4 cacc[4] = {};

  // ---------------- pass 2: P write (once) + ctx ----------------
  STAGE_K(0, 0);  // identical-data overlap with pass1 wrap stages: benign
  STAGE_V(0, 0);
  STAGE_K(1, 1);
  STAGE_V(1, 1);
  for (int t = 0; t < 16; ++t) {
    // t=0 queue: [wrapK0(4) wrapK1(4) K0(4) V0(4) | K1(4) V1(4)] -> vmcnt(8)
    // t>=1 queue: [K_t V_t (8) | stores_{t-1}(8) K_{t+1} V_{t+1}(8)] -> vmcnt(16)
    if (t == 0)
      asm volatile("s_waitcnt vmcnt(8)" ::: "memory");
    else
      asm volatile("s_waitcnt vmcnt(16)" ::: "memory");
    __builtin_amdgcn_s_barrier();
    FENCE();
    const int kv0 = t * 128;
    const int bf = t & 1;
    f32x4 s[8] = {};
#pragma unroll
    for (int ks = 0; ks < 2; ++ks) {
      const int ph = (ks * 4 + lg) ^ (lc & 7);
#pragma unroll
      for (int i = 0; i < 8; ++i) {
        const short8 af = *(const short8*)&Ks[bf][(i * 16 + lc) * 64 + ph * 8];
        s[i] = __builtin_amdgcn_mfma_f32_16x16x32_bf16(af, qf[ks], s[i], 0, 0, 0);
      }
    }
    const uint4 mw4 = *(const uint4*)&mwp[t * 4];
    const unsigned int mwa[4] = {mw4.x, mw4.y, mw4.z, mw4.w};
#pragma unroll
    for (int i = 0; i < 8; ++i) {
      const unsigned int w = mwa[i >> 1];
      float pv[4];
      u16 pb[4];
#pragma unroll
      for (int r = 0; r < 4; ++r) {
        const float bit = (float)((w >> ((i & 1) * 16 + lg * 4 + r)) & 1u);
        const float p = __expf(s[i][r] * 0.125f) * bit * linv;
        pv[r] = p;
        pb[r] = f2b(p);
      }
      *(float4*)&attng[(size_t)(q0 + ql) * Tt + kv0 + i * 16 + lg * 4] =
          make_float4(pv[0], pv[1], pv[2], pv[3]);
      const int chunk = i * 2 + (lg >> 1);
      const int ph2 = chunk ^ (lc & 7);
      *(uint2*)&Ps[ql * 128 + ph2 * 8 + (lg & 1) * 4] = *(uint2*)pb;
    }
    asm volatile("s_waitcnt lgkmcnt(0)" ::: "memory");
    __builtin_amdgcn_s_barrier();
    FENCE();
    // ctx += P @ V-tile
#pragma unroll
    for (int ks = 0; ks < 4; ++ks) {
      const short8 pa =
          *(const short8*)&Ps[ql * 128 + (((ks * 4 + lg) ^ (lc & 7))) * 8];
#pragma unroll
      for (int j2 = 0; j2 < 4; ++j2) {
        const int d = j2 * 16 + lc;
        const short8 vb2 =
            *(const short8*)&Vs[bf][d * 128 + (((ks * 4 + lg) ^ (d & 7))) * 8];
        cacc[j2] =
            __builtin_amdgcn_mfma_f32_16x16x32_bf16(pa, vb2, cacc[j2], 0, 0, 0);
      }
    }
    asm volatile("s_waitcnt lgkmcnt(0)" ::: "memory");
    __builtin_amdgcn_s_barrier();
    FENCE();
    STAGE_K((t + 2) & 15, bf);
    STAGE_V((t + 2) & 15, bf);
  }

  // ctx epilogue: bf16 split-head
#pragma unroll
  for (int j2 = 0; j2 < 4; ++j2)
#pragma unroll
    for (int r = 0; r < 4; ++r) {
      const int q = q0 + wv * 16 + lg * 4 + r;
      ctxg[(size_t)q * Hd + j2 * 16 + lc] = f2b(cacc[j2][r]);
    }
#undef STAGE_K
#undef STAGE_V
#undef FENCE
}

// ---------------------------------------------------------------------------
extern "C" void kernel_launch(void* const* d_in, const int* in_sizes, int n_in,
                              void* d_out, int out_size, void* d_ws,
                              size_t ws_size, hipStream_t stream) {
  const float* x = (const float*)d_in[0];
  const int* mask = (const int*)d_in[1];
  const float* Wq = (const float*)d_in[2];
  const float* bq = (const float*)d_in[3];
  const float* Wk = (const float*)d_in[4];
  const float* bk = (const float*)d_in[5];
  const float* Wv = (const float*)d_in[6];
  const float* bv = (const float*)d_in[7];
  const float* Wo = (const float*)d_in[8];
  const float* bo = (const float*)d_in[9];
  const float* W1 = (const float*)d_in[10];
  const float* b1 = (const float*)d_in[11];
  const float* W2 = (const float*)d_in[12];
  const float* b2 = (const float*)d_in[13];

  float* out = (float*)d_out;
  float* attn = out + (size_t)BT * Dd;

  char* w = (char*)d_ws;
  u16* xb = (u16*)w;      w += (size_t)BT * Dd * 2;
  u16* wqkvT = (u16*)w;   w += (size_t)Dd * 2304 * 2;
  u16* woT = (u16*)w;     w += (size_t)Dd * Dd * 2;
  u16* w1T = (u16*)w;     w += (size_t)Dd * Df * 2;
  u16* w2T = (u16*)w;     w += (size_t)Df * Dd * 2;
  float* biasc = (float*)w;            w += 2304 * 4;
  unsigned int* mwords = (unsigned int*)w; w += 256 * 4;
  u16* qb = (u16*)w;      w += (size_t)BT * Dd * 2;
  u16* kb = (u16*)w;      w += (size_t)BT * Dd * 2;
  u16* vtb = (u16*)w;     w += (size_t)BT * Dd * 2;
  u16* ctxb = (u16*)w;    w += (size_t)BT * Dd * 2;
  u16* ff1b = (u16*)w;    w += (size_t)BT * Df * 2;
  float* h = (float*)qb;  // overlays qb+kb (dead after attn_fused)
  u16* hb = vtb;          // overlays vtb (dead after attn_fused)

  dim3 blk(256);

  // all prep in one launch
  prep_all<<<dim3(9994), blk, 0, stream>>>(x, Wq, Wk, Wv, Wo, W1, W2, bq, bk,
                                           bv, mask, xb, wqkvT, woT, w1T, w2T,
                                           biasc, mwords);

  // fused QKV projection (N = 2304)
  mgemm<5><<<dim3(18, 64), blk, 0, stream>>>(xb, wqkvT, biasc, nullptr, qb, kb,
                                             vtb, Dd, 2304);

  // fused attention: attn (written once) + ctx
  attn_fused<<<dim3(32, 48), blk, 0, stream>>>(qb, kb, vtb, mwords, attn, ctxb);

  // h = x + ctx@Wo + bo   (fp32 + bf16)
  mgemm<2><<<dim3(6, 64), blk, 0, stream>>>(ctxb, woT, bo, x, h, hb, nullptr,
                                            Dd, Dd);

  // ff1 = gelu(h@W1 + b1) bf16
  mgemm<3><<<dim3(24, 64), blk, 0, stream>>>(hb, w1T, b1, nullptr, ff1b,
                                             nullptr, nullptr, Dd, Df);

  // out = h + ff1@W2 + b2
  mgemm<4><<<dim3(6, 64), blk, 0, stream>>>(ff1b, w2T, b2, h, out, nullptr,
                                            nullptr, Df, Dd);
}

// Round 7
// 602.414 us; speedup vs baseline: 1.4594x; 1.0564x over previous
//
#include <hip/hip_runtime.h>
#include <hip/hip_bf16.h>
#include <math.h>

typedef unsigned short u16;
typedef __attribute__((ext_vector_type(8))) short short8;
typedef __attribute__((ext_vector_type(4))) float f32x4;

constexpr int Bc = 4, Tt = 2048, Dd = 768, Hh = 12, Hd = 64, Df = 3072;
constexpr int BT = Bc * Tt;  // 8192

__device__ __forceinline__ u16 f2b(float x) {
  __hip_bfloat16 h = __float2bfloat16(x);
  return *reinterpret_cast<u16*>(&h);
}
__device__ __forceinline__ float gelu_exact(float g) {
  return 0.5f * g * (1.0f + erff(g * 0.70710678118654752440f));
}
__device__ __forceinline__ void gload16(const void* g, void* l) {
  __builtin_amdgcn_global_load_lds(
      (const __attribute__((address_space(1))) unsigned int*)g,
      (__attribute__((address_space(3))) unsigned int*)l, 16, 0, 0);
}

// ---------------------------------------------------------------------------
// 32x32 transpose tile: in [R][C] fp32 -> out [C][R] bf16
// ---------------------------------------------------------------------------
__device__ __forceinline__ void tr_tile(const float* __restrict__ in,
                                        u16* __restrict__ out, int R, int C,
                                        int bx, int by, float* sh) {
  const int tx = threadIdx.x & 31, ty = threadIdx.x >> 5;
  const int r0 = by * 32, c0 = bx * 32;
#pragma unroll
  for (int i = 0; i < 4; ++i)
    sh[(ty + i * 8) * 33 + tx] = in[(size_t)(r0 + ty + i * 8) * C + c0 + tx];
  __syncthreads();
#pragma unroll
  for (int i = 0; i < 4; ++i)
    out[(size_t)(c0 + ty + i * 8) * R + r0 + tx] = f2b(sh[tx * 33 + ty + i * 8]);
}

// ---------------------------------------------------------------------------
// One fused prep kernel, dispatched by block range.
// ---------------------------------------------------------------------------
__global__ __launch_bounds__(256) void prep_all(
    const float* __restrict__ x, const float* __restrict__ Wq,
    const float* __restrict__ Wk, const float* __restrict__ Wv,
    const float* __restrict__ Wo, const float* __restrict__ W1,
    const float* __restrict__ W2, const float* __restrict__ bq,
    const float* __restrict__ bk, const float* __restrict__ bv,
    const int* __restrict__ mask, u16* __restrict__ xb,
    u16* __restrict__ wqkvT, u16* __restrict__ woT, u16* __restrict__ w1T,
    u16* __restrict__ w2T, float* __restrict__ biasc,
    unsigned int* __restrict__ mwords) {
  __shared__ float sh[32 * 33];
  const int s = blockIdx.x;
  if (s < 3072) {
    int i = (s * 256 + threadIdx.x) * 8;
    float4 a = *(const float4*)&x[i];
    float4 b = *(const float4*)&x[i + 4];
    u16 t[8] = {f2b(a.x), f2b(a.y), f2b(a.z), f2b(a.w),
                f2b(b.x), f2b(b.y), f2b(b.z), f2b(b.w)};
    *(uint4*)&xb[i] = *(uint4*)t;
  } else if (s < 3648) {
    int u = s - 3072; tr_tile(Wq, wqkvT, Dd, Dd, u % 24, u / 24, sh);
  } else if (s < 4224) {
    int u = s - 3648; tr_tile(Wk, wqkvT + 768 * Dd, Dd, Dd, u % 24, u / 24, sh);
  } else if (s < 4800) {
    int u = s - 4224; tr_tile(Wv, wqkvT + 1536 * Dd, Dd, Dd, u % 24, u / 24, sh);
  } else if (s < 5376) {
    int u = s - 4800; tr_tile(Wo, woT, Dd, Dd, u % 24, u / 24, sh);
  } else if (s < 7680) {
    int u = s - 5376; tr_tile(W1, w1T, Dd, Df, u % 96, u / 96, sh);
  } else if (s < 9984) {
    int u = s - 7680; tr_tile(W2, w2T, Df, Dd, u % 24, u / 24, sh);
  } else if (s < 9993) {
    int i = (s - 9984) * 256 + threadIdx.x;  // 0..2303
    biasc[i] = (i < 768) ? bq[i] : (i < 1536) ? bk[i - 768] : bv[i - 1536];
  } else {
    // pack mask bits: mwords[b*64 + w] bit j = mask[b*2048 + w*32 + j]
    const int id = threadIdx.x;  // 0..255
    const int b_ = id >> 6, kv0 = (id & 63) * 32;
    unsigned int wbits = 0u;
    for (int j = 0; j < 32; ++j)
      wbits |= (mask[b_ * Tt + kv0 + j] ? 1u : 0u) << j;
    mwords[id] = wbits;
  }
}

// ---------------------------------------------------------------------------
// bf16 MFMA NT GEMM, 128x128 tile, BK=32, 4 waves.
// MODE 5: QKV fused (N=2304): Q split-head | K split-head | V^T [B,H,64,T]
// MODE 2: C0 fp32 h = add + acc + bias; C1 bf16 h  (Wo, A gathered split-head)
// MODE 3: C0 bf16 gelu(acc + bias)                 (FF1)
// MODE 4: C0 fp32 add + acc + bias                 (FF2)
// ---------------------------------------------------------------------------
template <int MODE>
__global__ __launch_bounds__(256) void mgemm(
    const u16* __restrict__ A, const u16* __restrict__ Bt,
    const float* __restrict__ bias, const float* __restrict__ add,
    void* __restrict__ C0, void* __restrict__ C1, void* __restrict__ C2,
    int K, int N) {
  __shared__ __align__(16) u16 As[128 * 32];
  __shared__ __align__(16) u16 Bs[128 * 32];
  const int tid = threadIdx.x;
  const int lane = tid & 63, wv = tid >> 6;
  const int m0 = blockIdx.y * 128, n0 = blockIdx.x * 128;
  const int wm = (wv >> 1) * 64, wn = (wv & 1) * 64;

  f32x4 acc[4][4] = {};

  for (int k0 = 0; k0 < K; k0 += 32) {
#pragma unroll
    for (int i = 0; i < 2; ++i) {
      const int idx = i * 256 + tid;
      const int row = idx >> 2;
      const int kc = (idx & 3) * 8;
      const u16* ga;
      if constexpr (MODE == 2) {
        const int m = m0 + row, b = m >> 11, t = m & 2047;
        const int kk = k0 + kc, head = kk >> 6, d = kk & 63;
        ga = &A[(((size_t)(b * Hh + head) * Tt + t) << 6) + d];
      } else {
        ga = &A[(size_t)(m0 + row) * K + k0 + kc];
      }
      gload16(ga, &As[idx * 8]);
      gload16(&Bt[(size_t)(n0 + row) * K + k0 + kc], &Bs[idx * 8]);
    }
    __syncthreads();
    short8 af[4], bfr[4];
#pragma unroll
    for (int i = 0; i < 4; ++i) {
      af[i] = *reinterpret_cast<const short8*>(
          &As[(wm + i * 16 + (lane & 15)) * 32 + (lane >> 4) * 8]);
      bfr[i] = *reinterpret_cast<const short8*>(
          &Bs[(wn + i * 16 + (lane & 15)) * 32 + (lane >> 4) * 8]);
    }
#pragma unroll
    for (int i = 0; i < 4; ++i)
#pragma unroll
      for (int j = 0; j < 4; ++j)
        acc[i][j] = __builtin_amdgcn_mfma_f32_16x16x32_bf16(af[i], bfr[j],
                                                            acc[i][j], 0, 0, 0);
    __syncthreads();
  }

  const int lr = (lane >> 4) * 4, lc = lane & 15;
#pragma unroll
  for (int i = 0; i < 4; ++i) {
    const int mbase = m0 + wm + i * 16 + lr;
#pragma unroll
    for (int j = 0; j < 4; ++j) {
      const int col = n0 + wn + j * 16 + lc;
      const float bvs = bias[col];
#pragma unroll
      for (int r = 0; r < 4; ++r) {
        const int m = mbase + r;
        float g = acc[i][j][r] + bvs;
        if constexpr (MODE == 5) {
          const int b = m >> 11, t = m & 2047;
          if (col < 768) {
            const int head = col >> 6, d = col & 63;
            ((u16*)C0)[(((size_t)(b * Hh + head) * Tt + t) << 6) + d] = f2b(g);
          } else if (col < 1536) {
            const int c = col - 768, head = c >> 6, d = c & 63;
            ((u16*)C1)[(((size_t)(b * Hh + head) * Tt + t) << 6) + d] = f2b(g);
          } else {
            const int c = col - 1536, head = c >> 6, d = c & 63;
            ((u16*)C2)[(((size_t)(b * Hh + head) * Hd + d) << 11) + t] = f2b(g);
          }
        } else if constexpr (MODE == 2) {
          g += add[(size_t)m * Dd + col];
          ((float*)C0)[(size_t)m * Dd + col] = g;
          ((u16*)C1)[(size_t)m * Dd + col] = f2b(g);
        } else if constexpr (MODE == 3) {
          ((u16*)C0)[(size_t)m * N + col] = f2b(gelu_exact(g));
        } else {
          g += add[(size_t)m * Dd + col];
          ((float*)C0)[(size_t)m * Dd + col] = g;
        }
      }
    }
  }
}

// ---------------------------------------------------------------------------
// Fused attention v5: coalesced attn stores.
// 64 q-rows/block, 4 waves (16 q-rows each).  Per kv-tile (128):
//   S^T = mfma(K,Q)  ->  p = exp(s/8)*maskbit*linv  ->  Pf32 LDS tile
//   (XOR-swizzled granules)  ->  PV MFMA (A-frag converted from Pf32)
//   ->  cooperative store: 512B-contiguous row segments (float4/lane).
// Each P row is produced & consumed by ONE wave -> Pf32 needs no barriers;
// only Ks/Vs staging does (2 syncthreads/tile).
// LDS: Ks 16K + Vs 16K + Pf 32K = 64KB -> 2 blocks/CU.
// ---------------------------------------------------------------------------
__global__ __launch_bounds__(256) void attn_fused(
    const u16* __restrict__ qb, const u16* __restrict__ kb,
    const u16* __restrict__ vtb, const unsigned int* __restrict__ mwords,
    float* __restrict__ attn, u16* __restrict__ ctxb) {
  const int bh = blockIdx.y;
  const int b = bh / Hh;
  const int q0 = blockIdx.x * 64;
  const u16* Qg = qb + (size_t)bh * Tt * Hd;
  const u16* Kg = kb + (size_t)bh * Tt * Hd;
  const u16* Vg = vtb + (size_t)bh * Hd * Tt;  // [64][2048]
  float* attng = attn + (size_t)bh * Tt * Tt;
  u16* ctxg = ctxb + (size_t)bh * Tt * Hd;
  const unsigned int* mwp = mwords + b * 64;

  __shared__ __align__(16) u16 Ks[128 * 64];
  __shared__ __align__(16) u16 Vs[64 * 128];
  __shared__ __align__(16) float Pf[64 * 128];

  const int tid = threadIdx.x, lane = tid & 63, wv = tid >> 6;
  const int lc = lane & 15, lg = lane >> 4;
  const int ql = wv * 16 + lc;   // local q row this lane owns as MFMA col
  const int qsw = lc & 7;        // row-XOR for Pf granules

#define STAGE_K(t)                                                          \
  {                                                                         \
    const int kv0_ = (t) * 128;                                             \
    _Pragma("unroll") for (int w_ = 0; w_ < 4; ++w_) {                      \
      const int p_ = w_ * 256 + tid;                                        \
      const int row_ = p_ >> 3, kc8_ = (p_ & 7) ^ (row_ & 7);               \
      gload16(Kg + (size_t)(kv0_ + row_) * Hd + kc8_ * 8, &Ks[p_ * 8]);     \
    }                                                                       \
  }
#define STAGE_V(t)                                                          \
  {                                                                         \
    const int kv0_ = (t) * 128;                                             \
    _Pragma("unroll") for (int w_ = 0; w_ < 4; ++w_) {                      \
      const int p_ = w_ * 256 + tid;                                        \
      const int d_ = p_ >> 4, pc_ = (p_ & 15) ^ (d_ & 7);                   \
      gload16(Vg + (size_t)d_ * Tt + kv0_ + pc_ * 8, &Vs[p_ * 8]);          \
    }                                                                       \
  }

  // Q fragments once, register-resident (B-operand; one-time gather)
  short8 qf[2];
#pragma unroll
  for (int ks = 0; ks < 2; ++ks)
    qf[ks] = *(const short8*)&Qg[(size_t)(q0 + ql) * Hd + ks * 32 + lg * 8];

  float l = 0.f;

  // ---------------- pass 1: row sums l ----------------
  for (int t = 0; t < 16; ++t) {
    STAGE_K(t);
    __syncthreads();
    f32x4 s[8] = {};
#pragma unroll
    for (int ks = 0; ks < 2; ++ks) {
      const int ph = (ks * 4 + lg) ^ qsw;
#pragma unroll
      for (int i = 0; i < 8; ++i) {
        const short8 af = *(const short8*)&Ks[(i * 16 + lc) * 64 + ph * 8];
        s[i] = __builtin_amdgcn_mfma_f32_16x16x32_bf16(af, qf[ks], s[i], 0, 0, 0);
      }
    }
    const uint4 mw4 = *(const uint4*)&mwp[t * 4];
    const unsigned int mwa[4] = {mw4.x, mw4.y, mw4.z, mw4.w};
    float ts = 0.f;
#pragma unroll
    for (int i = 0; i < 8; ++i) {
      const unsigned int w = mwa[i >> 1];
#pragma unroll
      for (int r = 0; r < 4; ++r) {
        const float bit = (float)((w >> ((i & 1) * 16 + lg * 4 + r)) & 1u);
        ts += __expf(s[i][r] * 0.125f) * bit;
      }
    }
    ts += __shfl_xor(ts, 16);
    ts += __shfl_xor(ts, 32);
    l += ts;
    __syncthreads();
  }

  const float linv = 1.f / l;
  f32x4 cacc[4] = {};

  // ---------------- pass 2: P -> Pf LDS -> ctx MFMA + coalesced store ------
  for (int t = 0; t < 16; ++t) {
    const int kv0 = t * 128;
    STAGE_K(t);
    STAGE_V(t);
    __syncthreads();
    f32x4 s[8] = {};
#pragma unroll
    for (int ks = 0; ks < 2; ++ks) {
      const int ph = (ks * 4 + lg) ^ qsw;
#pragma unroll
      for (int i = 0; i < 8; ++i) {
        const short8 af = *(const short8*)&Ks[(i * 16 + lc) * 64 + ph * 8];
        s[i] = __builtin_amdgcn_mfma_f32_16x16x32_bf16(af, qf[ks], s[i], 0, 0, 0);
      }
    }
    const uint4 mw4 = *(const uint4*)&mwp[t * 4];
    const unsigned int mwa[4] = {mw4.x, mw4.y, mw4.z, mw4.w};
#pragma unroll
    for (int i = 0; i < 8; ++i) {
      const unsigned int w = mwa[i >> 1];
      float pv[4];
#pragma unroll
      for (int r = 0; r < 4; ++r) {
        const float bit = (float)((w >> ((i & 1) * 16 + lg * 4 + r)) & 1u);
        pv[r] = __expf(s[i][r] * 0.125f) * bit * linv;
      }
      // P[ql][kv local i*16+lg*4 .. +4] -> granule (i*4+lg)^qsw
      const int g = (i * 4 + lg) ^ qsw;
      *(f32x4*)&Pf[ql * 128 + g * 4] = *(f32x4*)pv;
    }
    // ctx += P @ V-tile (pa converted from own-wave Pf rows; intra-wave dep)
#pragma unroll
    for (int ks = 0; ks < 4; ++ks) {
      const int gA = (ks * 8 + lg * 2) ^ qsw;
      const int gB = (ks * 8 + lg * 2 + 1) ^ qsw;
      const f32x4 fA = *(const f32x4*)&Pf[ql * 128 + gA * 4];
      const f32x4 fB = *(const f32x4*)&Pf[ql * 128 + gB * 4];
      u16 pb[8] = {f2b(fA[0]), f2b(fA[1]), f2b(fA[2]), f2b(fA[3]),
                   f2b(fB[0]), f2b(fB[1]), f2b(fB[2]), f2b(fB[3])};
      const short8 pa = *(const short8*)pb;
#pragma unroll
      for (int j2 = 0; j2 < 4; ++j2) {
        const int d = j2 * 16 + lc;
        const short8 vb2 =
            *(const short8*)&Vs[d * 128 + (((ks * 4 + lg) ^ (d & 7))) * 8];
        cacc[j2] =
            __builtin_amdgcn_mfma_f32_16x16x32_bf16(pa, vb2, cacc[j2], 0, 0, 0);
      }
    }
    // cooperative coalesced store: wave wv writes its own rows
#pragma unroll
    for (int it = 0; it < 8; ++it) {
      const int row = wv * 16 + it * 2 + (lane >> 5);
      const int colg = lane & 31;
      const int g2 = colg ^ (row & 7);
      const f32x4 v = *(const f32x4*)&Pf[row * 128 + g2 * 4];
      *(f32x4*)&attng[(size_t)(q0 + row) * Tt + kv0 + colg * 4] = v;
    }
    __syncthreads();
  }

  // ctx epilogue: bf16 split-head
#pragma unroll
  for (int j2 = 0; j2 < 4; ++j2)
#pragma unroll
    for (int r = 0; r < 4; ++r) {
      const int q = q0 + wv * 16 + lg * 4 + r;
      ctxg[(size_t)q * Hd + j2 * 16 + lc] = f2b(cacc[j2][r]);
    }
#undef STAGE_K
#undef STAGE_V
}

// ---------------------------------------------------------------------------
extern "C" void kernel_launch(void* const* d_in, const int* in_sizes, int n_in,
                              void* d_out, int out_size, void* d_ws,
                              size_t ws_size, hipStream_t stream) {
  const float* x = (const float*)d_in[0];
  const int* mask = (const int*)d_in[1];
  const float* Wq = (const float*)d_in[2];
  const float* bq = (const float*)d_in[3];
  const float* Wk = (const float*)d_in[4];
  const float* bk = (const float*)d_in[5];
  const float* Wv = (const float*)d_in[6];
  const float* bv = (const float*)d_in[7];
  const float* Wo = (const float*)d_in[8];
  const float* bo = (const float*)d_in[9];
  const float* W1 = (const float*)d_in[10];
  const float* b1 = (const float*)d_in[11];
  const float* W2 = (const float*)d_in[12];
  const float* b2 = (const float*)d_in[13];

  float* out = (float*)d_out;
  float* attn = out + (size_t)BT * Dd;

  char* w = (char*)d_ws;
  u16* xb = (u16*)w;      w += (size_t)BT * Dd * 2;
  u16* wqkvT = (u16*)w;   w += (size_t)Dd * 2304 * 2;
  u16* woT = (u16*)w;     w += (size_t)Dd * Dd * 2;
  u16* w1T = (u16*)w;     w += (size_t)Dd * Df * 2;
  u16* w2T = (u16*)w;     w += (size_t)Df * Dd * 2;
  float* biasc = (float*)w;            w += 2304 * 4;
  unsigned int* mwords = (unsigned int*)w; w += 256 * 4;
  u16* qb = (u16*)w;      w += (size_t)BT * Dd * 2;
  u16* kb = (u16*)w;      w += (size_t)BT * Dd * 2;
  u16* vtb = (u16*)w;     w += (size_t)BT * Dd * 2;
  u16* ctxb = (u16*)w;    w += (size_t)BT * Dd * 2;
  u16* ff1b = (u16*)w;    w += (size_t)BT * Df * 2;
  float* h = (float*)qb;  // overlays qb+kb (dead after attn_fused)
  u16* hb = vtb;          // overlays vtb (dead after attn_fused)

  dim3 blk(256);

  // all prep in one launch
  prep_all<<<dim3(9994), blk, 0, stream>>>(x, Wq, Wk, Wv, Wo, W1, W2, bq, bk,
                                           bv, mask, xb, wqkvT, woT, w1T, w2T,
                                           biasc, mwords);

  // fused QKV projection (N = 2304)
  mgemm<5><<<dim3(18, 64), blk, 0, stream>>>(xb, wqkvT, biasc, nullptr, qb, kb,
                                             vtb, Dd, 2304);

  // fused attention: attn (written once, coalesced) + ctx
  attn_fused<<<dim3(32, 48), blk, 0, stream>>>(qb, kb, vtb, mwords, attn, ctxb);

  // h = x + ctx@Wo + bo   (fp32 + bf16)
  mgemm<2><<<dim3(6, 64), blk, 0, stream>>>(ctxb, woT, bo, x, h, hb, nullptr,
                                            Dd, Dd);

  // ff1 = gelu(h@W1 + b1) bf16
  mgemm<3><<<dim3(24, 64), blk, 0, stream>>>(hb, w1T, b1, nullptr, ff1b,
                                             nullptr, nullptr, Dd, Df);

  // out = h + ff1@W2 + b2
  mgemm<4><<<dim3(6, 64), blk, 0, stream>>>(ff1b, w2T, b2, h, out, nullptr,
                                            nullptr, Df, Dd);
}

// Round 8
// 595.434 us; speedup vs baseline: 1.4765x; 1.0117x over previous
//
#include <hip/hip_runtime.h>
#include <hip/hip_bf16.h>
#include <math.h>

typedef unsigned short u16;
typedef __attribute__((ext_vector_type(8))) short short8;
typedef __attribute__((ext_vector_type(4))) float f32x4;

constexpr int Bc = 4, Tt = 2048, Dd = 768, Hh = 12, Hd = 64, Df = 3072;
constexpr int BT = Bc * Tt;  // 8192

__device__ __forceinline__ u16 f2b(float x) {
  __hip_bfloat16 h = __float2bfloat16(x);
  return *reinterpret_cast<u16*>(&h);
}
__device__ __forceinline__ float gelu_exact(float g) {
  return 0.5f * g * (1.0f + erff(g * 0.70710678118654752440f));
}
__device__ __forceinline__ void gload16(const void* g, void* l) {
  __builtin_amdgcn_global_load_lds(
      (const __attribute__((address_space(1))) unsigned int*)g,
      (__attribute__((address_space(3))) unsigned int*)l, 16, 0, 0);
}

// ---------------------------------------------------------------------------
// 32x32 transpose tile: in [R][C] fp32 -> out [C][R] bf16
// ---------------------------------------------------------------------------
__device__ __forceinline__ void tr_tile(const float* __restrict__ in,
                                        u16* __restrict__ out, int R, int C,
                                        int bx, int by, float* sh) {
  const int tx = threadIdx.x & 31, ty = threadIdx.x >> 5;
  const int r0 = by * 32, c0 = bx * 32;
#pragma unroll
  for (int i = 0; i < 4; ++i)
    sh[(ty + i * 8) * 33 + tx] = in[(size_t)(r0 + ty + i * 8) * C + c0 + tx];
  __syncthreads();
#pragma unroll
  for (int i = 0; i < 4; ++i)
    out[(size_t)(c0 + ty + i * 8) * R + r0 + tx] = f2b(sh[tx * 33 + ty + i * 8]);
}

// ---------------------------------------------------------------------------
// One fused prep kernel, dispatched by block range.
// ---------------------------------------------------------------------------
__global__ __launch_bounds__(256) void prep_all(
    const float* __restrict__ x, const float* __restrict__ Wq,
    const float* __restrict__ Wk, const float* __restrict__ Wv,
    const float* __restrict__ Wo, const float* __restrict__ W1,
    const float* __restrict__ W2, const float* __restrict__ bq,
    const float* __restrict__ bk, const float* __restrict__ bv,
    const int* __restrict__ mask, u16* __restrict__ xb,
    u16* __restrict__ wqkvT, u16* __restrict__ woT, u16* __restrict__ w1T,
    u16* __restrict__ w2T, float* __restrict__ biasc,
    unsigned int* __restrict__ mwords) {
  __shared__ float sh[32 * 33];
  const int s = blockIdx.x;
  if (s < 3072) {
    int i = (s * 256 + threadIdx.x) * 8;
    float4 a = *(const float4*)&x[i];
    float4 b = *(const float4*)&x[i + 4];
    u16 t[8] = {f2b(a.x), f2b(a.y), f2b(a.z), f2b(a.w),
                f2b(b.x), f2b(b.y), f2b(b.z), f2b(b.w)};
    *(uint4*)&xb[i] = *(uint4*)t;
  } else if (s < 3648) {
    int u = s - 3072; tr_tile(Wq, wqkvT, Dd, Dd, u % 24, u / 24, sh);
  } else if (s < 4224) {
    int u = s - 3648; tr_tile(Wk, wqkvT + 768 * Dd, Dd, Dd, u % 24, u / 24, sh);
  } else if (s < 4800) {
    int u = s - 4224; tr_tile(Wv, wqkvT + 1536 * Dd, Dd, Dd, u % 24, u / 24, sh);
  } else if (s < 5376) {
    int u = s - 4800; tr_tile(Wo, woT, Dd, Dd, u % 24, u / 24, sh);
  } else if (s < 7680) {
    int u = s - 5376; tr_tile(W1, w1T, Dd, Df, u % 96, u / 96, sh);
  } else if (s < 9984) {
    int u = s - 7680; tr_tile(W2, w2T, Df, Dd, u % 24, u / 24, sh);
  } else if (s < 9993) {
    int i = (s - 9984) * 256 + threadIdx.x;  // 0..2303
    biasc[i] = (i < 768) ? bq[i] : (i < 1536) ? bk[i - 768] : bv[i - 1536];
  } else {
    // pack mask bits: mwords[b*64 + w] bit j = mask[b*2048 + w*32 + j]
    const int id = threadIdx.x;  // 0..255
    const int b_ = id >> 6, kv0 = (id & 63) * 32;
    unsigned int wbits = 0u;
    for (int j = 0; j < 32; ++j)
      wbits |= (mask[b_ * Tt + kv0 + j] ? 1u : 0u) << j;
    mwords[id] = wbits;
  }
}

// ---------------------------------------------------------------------------
// bf16 MFMA NT GEMM, 128x128 tile, BK=32, 4 waves.
// MODE 5: QKV fused (N=2304): Q split-head | K split-head | V^T [B,H,64,T]
// MODE 2: C0 fp32 h = add + acc + bias; C1 bf16 h  (Wo, A gathered split-head)
// MODE 3: C0 bf16 gelu(acc + bias)                 (FF1)
// MODE 4: C0 fp32 add + acc + bias                 (FF2)
// ---------------------------------------------------------------------------
template <int MODE>
__global__ __launch_bounds__(256) void mgemm(
    const u16* __restrict__ A, const u16* __restrict__ Bt,
    const float* __restrict__ bias, const float* __restrict__ add,
    void* __restrict__ C0, void* __restrict__ C1, void* __restrict__ C2,
    int K, int N) {
  __shared__ __align__(16) u16 As[128 * 32];
  __shared__ __align__(16) u16 Bs[128 * 32];
  const int tid = threadIdx.x;
  const int lane = tid & 63, wv = tid >> 6;
  const int m0 = blockIdx.y * 128, n0 = blockIdx.x * 128;
  const int wm = (wv >> 1) * 64, wn = (wv & 1) * 64;

  f32x4 acc[4][4] = {};

  for (int k0 = 0; k0 < K; k0 += 32) {
#pragma unroll
    for (int i = 0; i < 2; ++i) {
      const int idx = i * 256 + tid;
      const int row = idx >> 2;
      const int kc = (idx & 3) * 8;
      const u16* ga;
      if constexpr (MODE == 2) {
        const int m = m0 + row, b = m >> 11, t = m & 2047;
        const int kk = k0 + kc, head = kk >> 6, d = kk & 63;
        ga = &A[(((size_t)(b * Hh + head) * Tt + t) << 6) + d];
      } else {
        ga = &A[(size_t)(m0 + row) * K + k0 + kc];
      }
      gload16(ga, &As[idx * 8]);
      gload16(&Bt[(size_t)(n0 + row) * K + k0 + kc], &Bs[idx * 8]);
    }
    __syncthreads();
    short8 af[4], bfr[4];
#pragma unroll
    for (int i = 0; i < 4; ++i) {
      af[i] = *reinterpret_cast<const short8*>(
          &As[(wm + i * 16 + (lane & 15)) * 32 + (lane >> 4) * 8]);
      bfr[i] = *reinterpret_cast<const short8*>(
          &Bs[(wn + i * 16 + (lane & 15)) * 32 + (lane >> 4) * 8]);
    }
#pragma unroll
    for (int i = 0; i < 4; ++i)
#pragma unroll
      for (int j = 0; j < 4; ++j)
        acc[i][j] = __builtin_amdgcn_mfma_f32_16x16x32_bf16(af[i], bfr[j],
                                                            acc[i][j], 0, 0, 0);
    __syncthreads();
  }

  const int lr = (lane >> 4) * 4, lc = lane & 15;
#pragma unroll
  for (int i = 0; i < 4; ++i) {
    const int mbase = m0 + wm + i * 16 + lr;
#pragma unroll
    for (int j = 0; j < 4; ++j) {
      const int col = n0 + wn + j * 16 + lc;
      const float bvs = bias[col];
#pragma unroll
      for (int r = 0; r < 4; ++r) {
        const int m = mbase + r;
        float g = acc[i][j][r] + bvs;
        if constexpr (MODE == 5) {
          const int b = m >> 11, t = m & 2047;
          if (col < 768) {
            const int head = col >> 6, d = col & 63;
            ((u16*)C0)[(((size_t)(b * Hh + head) * Tt + t) << 6) + d] = f2b(g);
          } else if (col < 1536) {
            const int c = col - 768, head = c >> 6, d = c & 63;
            ((u16*)C1)[(((size_t)(b * Hh + head) * Tt + t) << 6) + d] = f2b(g);
          } else {
            const int c = col - 1536, head = c >> 6, d = c & 63;
            ((u16*)C2)[(((size_t)(b * Hh + head) * Hd + d) << 11) + t] = f2b(g);
          }
        } else if constexpr (MODE == 2) {
          g += add[(size_t)m * Dd + col];
          ((float*)C0)[(size_t)m * Dd + col] = g;
          ((u16*)C1)[(size_t)m * Dd + col] = f2b(g);
        } else if constexpr (MODE == 3) {
          ((u16*)C0)[(size_t)m * N + col] = f2b(gelu_exact(g));
        } else {
          g += add[(size_t)m * Dd + col];
          ((float*)C0)[(size_t)m * Dd + col] = g;
        }
      }
    }
  }
}

// ---------------------------------------------------------------------------
// Fused attention v6: coalesced attn stores + counted vmcnt (stores float).
// 64 q-rows/block, 4 waves.  Pass 2 per tile:
//   vmcnt(8) [waits K_t,V_t; prev tile's 8 stores stay in flight] + s_barrier
//   -> stage K_{t+1} (dbuf, overlaps QK^T) -> QK^T -> exp -> Pf(LDS,f32)
//   -> PV MFMA -> s_barrier (V consumers done) -> stage V_{t+1} (single buf)
//   -> coalesced coop store of Pf (512B row segments), never drained in-loop.
// Pass 1: K dbuf, 1 barrier/tile, vmcnt(0) (queue holds only K loads).
// LDS: Ks 2x16K + Vs 16K + Pf 32K = 80KB -> 2 blocks/CU.
// ---------------------------------------------------------------------------
__global__ __launch_bounds__(256) void attn_fused(
    const u16* __restrict__ qb, const u16* __restrict__ kb,
    const u16* __restrict__ vtb, const unsigned int* __restrict__ mwords,
    float* __restrict__ attn, u16* __restrict__ ctxb) {
  const int bh = blockIdx.y;
  const int b = bh / Hh;
  const int q0 = blockIdx.x * 64;
  const u16* Qg = qb + (size_t)bh * Tt * Hd;
  const u16* Kg = kb + (size_t)bh * Tt * Hd;
  const u16* Vg = vtb + (size_t)bh * Hd * Tt;  // [64][2048]
  float* attng = attn + (size_t)bh * Tt * Tt;
  u16* ctxg = ctxb + (size_t)bh * Tt * Hd;
  const unsigned int* mwp = mwords + b * 64;

  __shared__ __align__(16) u16 Ks[2][128 * 64];
  __shared__ __align__(16) u16 Vs[64 * 128];
  __shared__ __align__(16) float Pf[64 * 128];

  const int tid = threadIdx.x, lane = tid & 63, wv = tid >> 6;
  const int lc = lane & 15, lg = lane >> 4;
  const int ql = wv * 16 + lc;   // local q row this lane owns as MFMA col
  const int qsw = lc & 7;        // row-XOR for Pf granules

#define STAGE_K(t, bf)                                                       \
  {                                                                          \
    const int kv0_ = (t) * 128;                                              \
    _Pragma("unroll") for (int w_ = 0; w_ < 4; ++w_) {                       \
      const int p_ = w_ * 256 + tid;                                         \
      const int row_ = p_ >> 3, kc8_ = (p_ & 7) ^ (row_ & 7);                \
      gload16(Kg + (size_t)(kv0_ + row_) * Hd + kc8_ * 8, &Ks[bf][p_ * 8]);  \
    }                                                                        \
  }
#define STAGE_V(t)                                                           \
  {                                                                          \
    const int kv0_ = (t) * 128;                                              \
    _Pragma("unroll") for (int w_ = 0; w_ < 4; ++w_) {                       \
      const int p_ = w_ * 256 + tid;                                         \
      const int d_ = p_ >> 4, pc_ = (p_ & 15) ^ (d_ & 7);                    \
      gload16(Vg + (size_t)d_ * Tt + kv0_ + pc_ * 8, &Vs[p_ * 8]);           \
    }                                                                        \
  }
#define FENCE() asm volatile("" ::: "memory")

  // Q fragments once, register-resident (B-operand; one-time gather)
  short8 qf[2];
#pragma unroll
  for (int ks = 0; ks < 2; ++ks)
    qf[ks] = *(const short8*)&Qg[(size_t)(q0 + ql) * Hd + ks * 32 + lg * 8];

  float l = 0.f;

  // ---------------- pass 1: row sums l ----------------
  STAGE_K(0, 0);
  for (int t = 0; t < 16; ++t) {
    asm volatile("s_waitcnt vmcnt(0)" ::: "memory");
    __builtin_amdgcn_s_barrier();
    FENCE();
    const int bf = t & 1;
    if (t < 15) STAGE_K(t + 1, bf ^ 1);
    f32x4 s[8] = {};
#pragma unroll
    for (int ks = 0; ks < 2; ++ks) {
      const int ph = (ks * 4 + lg) ^ qsw;
#pragma unroll
      for (int i = 0; i < 8; ++i) {
        const short8 af = *(const short8*)&Ks[bf][(i * 16 + lc) * 64 + ph * 8];
        s[i] = __builtin_amdgcn_mfma_f32_16x16x32_bf16(af, qf[ks], s[i], 0, 0, 0);
      }
    }
    const uint4 mw4 = *(const uint4*)&mwp[t * 4];
    const unsigned int mwa[4] = {mw4.x, mw4.y, mw4.z, mw4.w};
    float ts = 0.f;
#pragma unroll
    for (int i = 0; i < 8; ++i) {
      const unsigned int w = mwa[i >> 1];
#pragma unroll
      for (int r = 0; r < 4; ++r) {
        const float bit = (float)((w >> ((i & 1) * 16 + lg * 4 + r)) & 1u);
        ts += __expf(s[i][r] * 0.125f) * bit;
      }
    }
    ts += __shfl_xor(ts, 16);
    ts += __shfl_xor(ts, 32);
    l += ts;
  }

  const float linv = 1.f / l;
  f32x4 cacc[4] = {};

  // barrier so pass-2 staging can't race pass-1's last reads of Ks[1]
  __builtin_amdgcn_s_barrier();
  FENCE();

  // ---------------- pass 2: P -> Pf -> ctx MFMA + floating coalesced store --
  STAGE_K(0, 0);
  STAGE_V(0);
  for (int t = 0; t < 16; ++t) {
    const int kv0 = t * 128;
    const int bf = t & 1;
    if (t == 0)
      asm volatile("s_waitcnt vmcnt(0)" ::: "memory");
    else
      asm volatile("s_waitcnt vmcnt(8)" ::: "memory");  // stores_{t-1} float
    __builtin_amdgcn_s_barrier();
    FENCE();
    if (t < 15) STAGE_K(t + 1, bf ^ 1);  // overlaps QK^T below
    f32x4 s[8] = {};
#pragma unroll
    for (int ks = 0; ks < 2; ++ks) {
      const int ph = (ks * 4 + lg) ^ qsw;
#pragma unroll
      for (int i = 0; i < 8; ++i) {
        const short8 af = *(const short8*)&Ks[bf][(i * 16 + lc) * 64 + ph * 8];
        s[i] = __builtin_amdgcn_mfma_f32_16x16x32_bf16(af, qf[ks], s[i], 0, 0, 0);
      }
    }
    const uint4 mw4 = *(const uint4*)&mwp[t * 4];
    const unsigned int mwa[4] = {mw4.x, mw4.y, mw4.z, mw4.w};
#pragma unroll
    for (int i = 0; i < 8; ++i) {
      const unsigned int w = mwa[i >> 1];
      float pv[4];
#pragma unroll
      for (int r = 0; r < 4; ++r) {
        const float bit = (float)((w >> ((i & 1) * 16 + lg * 4 + r)) & 1u);
        pv[r] = __expf(s[i][r] * 0.125f) * bit * linv;
      }
      const int g = (i * 4 + lg) ^ qsw;  // granule swizzle
      *(f32x4*)&Pf[ql * 128 + g * 4] = *(f32x4*)pv;
    }
    // ctx += P @ V-tile (intra-wave Pf dep; compiler orders lgkm)
#pragma unroll
    for (int ks = 0; ks < 4; ++ks) {
      const int gA = (ks * 8 + lg * 2) ^ qsw;
      const int gB = (ks * 8 + lg * 2 + 1) ^ qsw;
      const f32x4 fA = *(const f32x4*)&Pf[ql * 128 + gA * 4];
      const f32x4 fB = *(const f32x4*)&Pf[ql * 128 + gB * 4];
      u16 pb[8] = {f2b(fA[0]), f2b(fA[1]), f2b(fA[2]), f2b(fA[3]),
                   f2b(fB[0]), f2b(fB[1]), f2b(fB[2]), f2b(fB[3])};
      const short8 pa = *(const short8*)pb;
#pragma unroll
      for (int j2 = 0; j2 < 4; ++j2) {
        const int d = j2 * 16 + lc;
        const short8 vb2 =
            *(const short8*)&Vs[d * 128 + (((ks * 4 + lg) ^ (d & 7))) * 8];
        cacc[j2] =
            __builtin_amdgcn_mfma_f32_16x16x32_bf16(pa, vb2, cacc[j2], 0, 0, 0);
      }
    }
    // all waves done reading Vs -> safe to restage V (no vmcnt drain here)
    __builtin_amdgcn_s_barrier();
    FENCE();
    if (t < 15) STAGE_V(t + 1);
    // cooperative coalesced store (floats until vmcnt(8) two tiles later)
#pragma unroll
    for (int it = 0; it < 8; ++it) {
      const int row = wv * 16 + it * 2 + (lane >> 5);
      const int colg = lane & 31;
      const int g2 = colg ^ (row & 7);
      const f32x4 v = *(const f32x4*)&Pf[row * 128 + g2 * 4];
      *(f32x4*)&attng[(size_t)(q0 + row) * Tt + kv0 + colg * 4] = v;
    }
  }

  // ctx epilogue: bf16 split-head
#pragma unroll
  for (int j2 = 0; j2 < 4; ++j2)
#pragma unroll
    for (int r = 0; r < 4; ++r) {
      const int q = q0 + wv * 16 + lg * 4 + r;
      ctxg[(size_t)q * Hd + j2 * 16 + lc] = f2b(cacc[j2][r]);
    }
#undef STAGE_K
#undef STAGE_V
#undef FENCE
}

// ---------------------------------------------------------------------------
extern "C" void kernel_launch(void* const* d_in, const int* in_sizes, int n_in,
                              void* d_out, int out_size, void* d_ws,
                              size_t ws_size, hipStream_t stream) {
  const float* x = (const float*)d_in[0];
  const int* mask = (const int*)d_in[1];
  const float* Wq = (const float*)d_in[2];
  const float* bq = (const float*)d_in[3];
  const float* Wk = (const float*)d_in[4];
  const float* bk = (const float*)d_in[5];
  const float* Wv = (const float*)d_in[6];
  const float* bv = (const float*)d_in[7];
  const float* Wo = (const float*)d_in[8];
  const float* bo = (const float*)d_in[9];
  const float* W1 = (const float*)d_in[10];
  const float* b1 = (const float*)d_in[11];
  const float* W2 = (const float*)d_in[12];
  const float* b2 = (const float*)d_in[13];

  float* out = (float*)d_out;
  float* attn = out + (size_t)BT * Dd;

  char* w = (char*)d_ws;
  u16* xb = (u16*)w;      w += (size_t)BT * Dd * 2;
  u16* wqkvT = (u16*)w;   w += (size_t)Dd * 2304 * 2;
  u16* woT = (u16*)w;     w += (size_t)Dd * Dd * 2;
  u16* w1T = (u16*)w;     w += (size_t)Dd * Df * 2;
  u16* w2T = (u16*)w;     w += (size_t)Df * Dd * 2;
  float* biasc = (float*)w;            w += 2304 * 4;
  unsigned int* mwords = (unsigned int*)w; w += 256 * 4;
  u16* qb = (u16*)w;      w += (size_t)BT * Dd * 2;
  u16* kb = (u16*)w;      w += (size_t)BT * Dd * 2;
  u16* vtb = (u16*)w;     w += (size_t)BT * Dd * 2;
  u16* ctxb = (u16*)w;    w += (size_t)BT * Dd * 2;
  u16* ff1b = (u16*)w;    w += (size_t)BT * Df * 2;
  float* h = (float*)qb;  // overlays qb+kb (dead after attn_fused)
  u16* hb = vtb;          // overlays vtb (dead after attn_fused)

  dim3 blk(256);

  // all prep in one launch
  prep_all<<<dim3(9994), blk, 0, stream>>>(x, Wq, Wk, Wv, Wo, W1, W2, bq, bk,
                                           bv, mask, xb, wqkvT, woT, w1T, w2T,
                                           biasc, mwords);

  // fused QKV projection (N = 2304)
  mgemm<5><<<dim3(18, 64), blk, 0, stream>>>(xb, wqkvT, biasc, nullptr, qb, kb,
                                             vtb, Dd, 2304);

  // fused attention: attn (written once, coalesced, floating) + ctx
  attn_fused<<<dim3(32, 48), blk, 0, stream>>>(qb, kb, vtb, mwords, attn, ctxb);

  // h = x + ctx@Wo + bo   (fp32 + bf16)
  mgemm<2><<<dim3(6, 64), blk, 0, stream>>>(ctxb, woT, bo, x, h, hb, nullptr,
                                            Dd, Dd);

  // ff1 = gelu(h@W1 + b1) bf16
  mgemm<3><<<dim3(24, 64), blk, 0, stream>>>(hb, w1T, b1, nullptr, ff1b,
                                             nullptr, nullptr, Dd, Df);

  // out = h + ff1@W2 + b2
  mgemm<4><<<dim3(6, 64), blk, 0, stream>>>(ff1b, w2T, b2, h, out, nullptr,
                                            nullptr, Df, Dd);
}

// Round 9
// 476.766 us; speedup vs baseline: 1.8440x; 1.2489x over previous
//
#include <hip/hip_runtime.h>
#include <hip/hip_bf16.h>
#include <math.h>

typedef unsigned short u16;
typedef __attribute__((ext_vector_type(8))) short short8;
typedef __attribute__((ext_vector_type(4))) float f32x4;

constexpr int Bc = 4, Tt = 2048, Dd = 768, Hh = 12, Hd = 64, Df = 3072;
constexpr int BT = Bc * Tt;  // 8192

__device__ __forceinline__ u16 f2b(float x) {
  __hip_bfloat16 h = __float2bfloat16(x);
  return *reinterpret_cast<u16*>(&h);
}
__device__ __forceinline__ float gelu_exact(float g) {
  return 0.5f * g * (1.0f + erff(g * 0.70710678118654752440f));
}
__device__ __forceinline__ void gload16(const void* g, void* l) {
  __builtin_amdgcn_global_load_lds(
      (const __attribute__((address_space(1))) unsigned int*)g,
      (__attribute__((address_space(3))) unsigned int*)l, 16, 0, 0);
}

// ---------------------------------------------------------------------------
// 32x32 transpose tile: in [R][C] fp32 -> out [C][R] bf16
// ---------------------------------------------------------------------------
__device__ __forceinline__ void tr_tile(const float* __restrict__ in,
                                        u16* __restrict__ out, int R, int C,
                                        int bx, int by, float* sh) {
  const int tx = threadIdx.x & 31, ty = threadIdx.x >> 5;
  const int r0 = by * 32, c0 = bx * 32;
#pragma unroll
  for (int i = 0; i < 4; ++i)
    sh[(ty + i * 8) * 33 + tx] = in[(size_t)(r0 + ty + i * 8) * C + c0 + tx];
  __syncthreads();
#pragma unroll
  for (int i = 0; i < 4; ++i)
    out[(size_t)(c0 + ty + i * 8) * R + r0 + tx] = f2b(sh[tx * 33 + ty + i * 8]);
}

// ---------------------------------------------------------------------------
// One fused prep kernel, dispatched by block range.
// ---------------------------------------------------------------------------
__global__ __launch_bounds__(256) void prep_all(
    const float* __restrict__ x, const float* __restrict__ Wq,
    const float* __restrict__ Wk, const float* __restrict__ Wv,
    const float* __restrict__ Wo, const float* __restrict__ W1,
    const float* __restrict__ W2, const float* __restrict__ bq,
    const float* __restrict__ bk, const float* __restrict__ bv,
    const int* __restrict__ mask, u16* __restrict__ xb,
    u16* __restrict__ wqkvT, u16* __restrict__ woT, u16* __restrict__ w1T,
    u16* __restrict__ w2T, float* __restrict__ biasc,
    unsigned int* __restrict__ mwords) {
  __shared__ float sh[32 * 33];
  const int s = blockIdx.x;
  if (s < 3072) {
    int i = (s * 256 + threadIdx.x) * 8;
    float4 a = *(const float4*)&x[i];
    float4 b = *(const float4*)&x[i + 4];
    u16 t[8] = {f2b(a.x), f2b(a.y), f2b(a.z), f2b(a.w),
                f2b(b.x), f2b(b.y), f2b(b.z), f2b(b.w)};
    *(uint4*)&xb[i] = *(uint4*)t;
  } else if (s < 3648) {
    int u = s - 3072; tr_tile(Wq, wqkvT, Dd, Dd, u % 24, u / 24, sh);
  } else if (s < 4224) {
    int u = s - 3648; tr_tile(Wk, wqkvT + 768 * Dd, Dd, Dd, u % 24, u / 24, sh);
  } else if (s < 4800) {
    int u = s - 4224; tr_tile(Wv, wqkvT + 1536 * Dd, Dd, Dd, u % 24, u / 24, sh);
  } else if (s < 5376) {
    int u = s - 4800; tr_tile(Wo, woT, Dd, Dd, u % 24, u / 24, sh);
  } else if (s < 7680) {
    int u = s - 5376; tr_tile(W1, w1T, Dd, Df, u % 96, u / 96, sh);
  } else if (s < 9984) {
    int u = s - 7680; tr_tile(W2, w2T, Df, Dd, u % 24, u / 24, sh);
  } else if (s < 9993) {
    int i = (s - 9984) * 256 + threadIdx.x;  // 0..2303
    biasc[i] = (i < 768) ? bq[i] : (i < 1536) ? bk[i - 768] : bv[i - 1536];
  } else {
    // pack mask bits: mwords[b*64 + w] bit j = mask[b*2048 + w*32 + j]
    const int id = threadIdx.x;  // 0..255
    const int b_ = id >> 6, kv0 = (id & 63) * 32;
    unsigned int wbits = 0u;
    for (int j = 0; j < 32; ++j)
      wbits |= (mask[b_ * Tt + kv0 + j] ? 1u : 0u) << j;
    mwords[id] = wbits;
  }
}

// ---------------------------------------------------------------------------
// bf16 MFMA NT GEMM, 128x128 tile, BK=32, 4 waves, DOUBLE-BUFFERED LDS:
// stage k+1 issued BEFORE compute of k; single __syncthreads per K-step
// (its vmcnt0 drain waits loads that overlapped the whole MFMA phase).
// MODE 5: QKV fused (N=2304): Q split-head | K split-head | V^T [B,H,64,T]
// MODE 2: C0 fp32 h = add + acc + bias; C1 bf16 h  (Wo, A gathered split-head)
// MODE 3: C0 bf16 gelu(acc + bias)                 (FF1)
// MODE 4: C0 fp32 add + acc + bias                 (FF2)
// ---------------------------------------------------------------------------
template <int MODE>
__global__ __launch_bounds__(256) void mgemm(
    const u16* __restrict__ A, const u16* __restrict__ Bt,
    const float* __restrict__ bias, const float* __restrict__ add,
    void* __restrict__ C0, void* __restrict__ C1, void* __restrict__ C2,
    int K, int N) {
  __shared__ __align__(16) u16 As[2][128 * 32];
  __shared__ __align__(16) u16 Bs[2][128 * 32];
  const int tid = threadIdx.x;
  const int lane = tid & 63, wv = tid >> 6;
  const int m0 = blockIdx.y * 128, n0 = blockIdx.x * 128;
  const int wm = (wv >> 1) * 64, wn = (wv & 1) * 64;

  f32x4 acc[4][4] = {};

#define MG_STAGE(k0_, bf_)                                                    \
  {                                                                           \
    _Pragma("unroll") for (int i_ = 0; i_ < 2; ++i_) {                        \
      const int idx_ = i_ * 256 + tid;                                        \
      const int row_ = idx_ >> 2;                                             \
      const int kc_ = (idx_ & 3) * 8;                                         \
      const u16* ga_;                                                         \
      if constexpr (MODE == 2) {                                              \
        const int m_ = m0 + row_, b_ = m_ >> 11, t_ = m_ & 2047;              \
        const int kk_ = (k0_) + kc_, hd_ = kk_ >> 6, d_ = kk_ & 63;           \
        ga_ = &A[(((size_t)(b_ * Hh + hd_) * Tt + t_) << 6) + d_];            \
      } else {                                                                \
        ga_ = &A[(size_t)(m0 + row_) * K + (k0_) + kc_];                      \
      }                                                                       \
      gload16(ga_, &As[bf_][idx_ * 8]);                                       \
      gload16(&Bt[(size_t)(n0 + row_) * K + (k0_) + kc_], &Bs[bf_][idx_ * 8]);\
    }                                                                         \
  }

  MG_STAGE(0, 0);
  __syncthreads();

  int it = 0;
  for (int k0 = 0; k0 < K; k0 += 32, ++it) {
    const int cur = it & 1;
    if (k0 + 32 < K) MG_STAGE(k0 + 32, cur ^ 1);  // overlaps compute below
    short8 af[4], bfr[4];
#pragma unroll
    for (int i = 0; i < 4; ++i) {
      af[i] = *reinterpret_cast<const short8*>(
          &As[cur][(wm + i * 16 + (lane & 15)) * 32 + (lane >> 4) * 8]);
      bfr[i] = *reinterpret_cast<const short8*>(
          &Bs[cur][(wn + i * 16 + (lane & 15)) * 32 + (lane >> 4) * 8]);
    }
#pragma unroll
    for (int i = 0; i < 4; ++i)
#pragma unroll
      for (int j = 0; j < 4; ++j)
        acc[i][j] = __builtin_amdgcn_mfma_f32_16x16x32_bf16(af[i], bfr[j],
                                                            acc[i][j], 0, 0, 0);
    __syncthreads();  // drains next-tile staging (overlapped) + LDS reads
  }
#undef MG_STAGE

  const int lr = (lane >> 4) * 4, lc = lane & 15;
#pragma unroll
  for (int i = 0; i < 4; ++i) {
    const int mbase = m0 + wm + i * 16 + lr;
#pragma unroll
    for (int j = 0; j < 4; ++j) {
      const int col = n0 + wn + j * 16 + lc;
      const float bvs = bias[col];
#pragma unroll
      for (int r = 0; r < 4; ++r) {
        const int m = mbase + r;
        float g = acc[i][j][r] + bvs;
        if constexpr (MODE == 5) {
          const int b = m >> 11, t = m & 2047;
          if (col < 768) {
            const int head = col >> 6, d = col & 63;
            ((u16*)C0)[(((size_t)(b * Hh + head) * Tt + t) << 6) + d] = f2b(g);
          } else if (col < 1536) {
            const int c = col - 768, head = c >> 6, d = c & 63;
            ((u16*)C1)[(((size_t)(b * Hh + head) * Tt + t) << 6) + d] = f2b(g);
          } else {
            const int c = col - 1536, head = c >> 6, d = c & 63;
            ((u16*)C2)[(((size_t)(b * Hh + head) * Hd + d) << 11) + t] = f2b(g);
          }
        } else if constexpr (MODE == 2) {
          g += add[(size_t)m * Dd + col];
          ((float*)C0)[(size_t)m * Dd + col] = g;
          ((u16*)C1)[(size_t)m * Dd + col] = f2b(g);
        } else if constexpr (MODE == 3) {
          ((u16*)C0)[(size_t)m * N + col] = f2b(gelu_exact(g));
        } else {
          g += add[(size_t)m * Dd + col];
          ((float*)C0)[(size_t)m * Dd + col] = g;
        }
      }
    }
  }
}

// ---------------------------------------------------------------------------
// Fused attention v7: r8 structure + NONTEMPORAL attn stores (write-once
// data bypasses L2, stops thrashing K/V + downstream working sets).
// ---------------------------------------------------------------------------
__global__ __launch_bounds__(256) void attn_fused(
    const u16* __restrict__ qb, const u16* __restrict__ kb,
    const u16* __restrict__ vtb, const unsigned int* __restrict__ mwords,
    float* __restrict__ attn, u16* __restrict__ ctxb) {
  const int bh = blockIdx.y;
  const int b = bh / Hh;
  const int q0 = blockIdx.x * 64;
  const u16* Qg = qb + (size_t)bh * Tt * Hd;
  const u16* Kg = kb + (size_t)bh * Tt * Hd;
  const u16* Vg = vtb + (size_t)bh * Hd * Tt;  // [64][2048]
  float* attng = attn + (size_t)bh * Tt * Tt;
  u16* ctxg = ctxb + (size_t)bh * Tt * Hd;
  const unsigned int* mwp = mwords + b * 64;

  __shared__ __align__(16) u16 Ks[2][128 * 64];
  __shared__ __align__(16) u16 Vs[64 * 128];
  __shared__ __align__(16) float Pf[64 * 128];

  const int tid = threadIdx.x, lane = tid & 63, wv = tid >> 6;
  const int lc = lane & 15, lg = lane >> 4;
  const int ql = wv * 16 + lc;   // local q row this lane owns as MFMA col
  const int qsw = lc & 7;        // row-XOR for Pf granules

#define STAGE_K(t, bf)                                                       \
  {                                                                          \
    const int kv0_ = (t) * 128;                                              \
    _Pragma("unroll") for (int w_ = 0; w_ < 4; ++w_) {                       \
      const int p_ = w_ * 256 + tid;                                         \
      const int row_ = p_ >> 3, kc8_ = (p_ & 7) ^ (row_ & 7);                \
      gload16(Kg + (size_t)(kv0_ + row_) * Hd + kc8_ * 8, &Ks[bf][p_ * 8]);  \
    }                                                                        \
  }
#define STAGE_V(t)                                                           \
  {                                                                          \
    const int kv0_ = (t) * 128;                                              \
    _Pragma("unroll") for (int w_ = 0; w_ < 4; ++w_) {                       \
      const int p_ = w_ * 256 + tid;                                         \
      const int d_ = p_ >> 4, pc_ = (p_ & 15) ^ (d_ & 7);                    \
      gload16(Vg + (size_t)d_ * Tt + kv0_ + pc_ * 8, &Vs[p_ * 8]);           \
    }                                                                        \
  }
#define FENCE() asm volatile("" ::: "memory")

  // Q fragments once, register-resident (B-operand; one-time gather)
  short8 qf[2];
#pragma unroll
  for (int ks = 0; ks < 2; ++ks)
    qf[ks] = *(const short8*)&Qg[(size_t)(q0 + ql) * Hd + ks * 32 + lg * 8];

  float l = 0.f;

  // ---------------- pass 1: row sums l ----------------
  STAGE_K(0, 0);
  for (int t = 0; t < 16; ++t) {
    asm volatile("s_waitcnt vmcnt(0)" ::: "memory");
    __builtin_amdgcn_s_barrier();
    FENCE();
    const int bf = t & 1;
    if (t < 15) STAGE_K(t + 1, bf ^ 1);
    f32x4 s[8] = {};
#pragma unroll
    for (int ks = 0; ks < 2; ++ks) {
      const int ph = (ks * 4 + lg) ^ qsw;
#pragma unroll
      for (int i = 0; i < 8; ++i) {
        const short8 af = *(const short8*)&Ks[bf][(i * 16 + lc) * 64 + ph * 8];
        s[i] = __builtin_amdgcn_mfma_f32_16x16x32_bf16(af, qf[ks], s[i], 0, 0, 0);
      }
    }
    const uint4 mw4 = *(const uint4*)&mwp[t * 4];
    const unsigned int mwa[4] = {mw4.x, mw4.y, mw4.z, mw4.w};
    float ts = 0.f;
#pragma unroll
    for (int i = 0; i < 8; ++i) {
      const unsigned int w = mwa[i >> 1];
#pragma unroll
      for (int r = 0; r < 4; ++r) {
        const float bit = (float)((w >> ((i & 1) * 16 + lg * 4 + r)) & 1u);
        ts += __expf(s[i][r] * 0.125f) * bit;
      }
    }
    ts += __shfl_xor(ts, 16);
    ts += __shfl_xor(ts, 32);
    l += ts;
  }

  const float linv = 1.f / l;
  f32x4 cacc[4] = {};

  // barrier so pass-2 staging can't race pass-1's last reads of Ks[1]
  __builtin_amdgcn_s_barrier();
  FENCE();

  // ---------------- pass 2: P -> Pf -> ctx MFMA + floating nt store --------
  STAGE_K(0, 0);
  STAGE_V(0);
  for (int t = 0; t < 16; ++t) {
    const int kv0 = t * 128;
    const int bf = t & 1;
    if (t == 0)
      asm volatile("s_waitcnt vmcnt(0)" ::: "memory");
    else
      asm volatile("s_waitcnt vmcnt(8)" ::: "memory");  // stores_{t-1} float
    __builtin_amdgcn_s_barrier();
    FENCE();
    if (t < 15) STAGE_K(t + 1, bf ^ 1);  // overlaps QK^T below
    f32x4 s[8] = {};
#pragma unroll
    for (int ks = 0; ks < 2; ++ks) {
      const int ph = (ks * 4 + lg) ^ qsw;
#pragma unroll
      for (int i = 0; i < 8; ++i) {
        const short8 af = *(const short8*)&Ks[bf][(i * 16 + lc) * 64 + ph * 8];
        s[i] = __builtin_amdgcn_mfma_f32_16x16x32_bf16(af, qf[ks], s[i], 0, 0, 0);
      }
    }
    const uint4 mw4 = *(const uint4*)&mwp[t * 4];
    const unsigned int mwa[4] = {mw4.x, mw4.y, mw4.z, mw4.w};
#pragma unroll
    for (int i = 0; i < 8; ++i) {
      const unsigned int w = mwa[i >> 1];
      float pv[4];
#pragma unroll
      for (int r = 0; r < 4; ++r) {
        const float bit = (float)((w >> ((i & 1) * 16 + lg * 4 + r)) & 1u);
        pv[r] = __expf(s[i][r] * 0.125f) * bit * linv;
      }
      const int g = (i * 4 + lg) ^ qsw;  // granule swizzle
      *(f32x4*)&Pf[ql * 128 + g * 4] = *(f32x4*)pv;
    }
    // ctx += P @ V-tile (intra-wave Pf dep; compiler orders lgkm)
#pragma unroll
    for (int ks = 0; ks < 4; ++ks) {
      const int gA = (ks * 8 + lg * 2) ^ qsw;
      const int gB = (ks * 8 + lg * 2 + 1) ^ qsw;
      const f32x4 fA = *(const f32x4*)&Pf[ql * 128 + gA * 4];
      const f32x4 fB = *(const f32x4*)&Pf[ql * 128 + gB * 4];
      u16 pb[8] = {f2b(fA[0]), f2b(fA[1]), f2b(fA[2]), f2b(fA[3]),
                   f2b(fB[0]), f2b(fB[1]), f2b(fB[2]), f2b(fB[3])};
      const short8 pa = *(const short8*)pb;
#pragma unroll
      for (int j2 = 0; j2 < 4; ++j2) {
        const int d = j2 * 16 + lc;
        const short8 vb2 =
            *(const short8*)&Vs[d * 128 + (((ks * 4 + lg) ^ (d & 7))) * 8];
        cacc[j2] =
            __builtin_amdgcn_mfma_f32_16x16x32_bf16(pa, vb2, cacc[j2], 0, 0, 0);
      }
    }
    // all waves done reading Vs -> safe to restage V (no vmcnt drain here)
    __builtin_amdgcn_s_barrier();
    FENCE();
    if (t < 15) STAGE_V(t + 1);
    // cooperative coalesced NONTEMPORAL store (floats until vmcnt(8) later)
#pragma unroll
    for (int it = 0; it < 8; ++it) {
      const int row = wv * 16 + it * 2 + (lane >> 5);
      const int colg = lane & 31;
      const int g2 = colg ^ (row & 7);
      const f32x4 v = *(const f32x4*)&Pf[row * 128 + g2 * 4];
      __builtin_nontemporal_store(
          v, (f32x4*)&attng[(size_t)(q0 + row) * Tt + kv0 + colg * 4]);
    }
  }

  // ctx epilogue: bf16 split-head
#pragma unroll
  for (int j2 = 0; j2 < 4; ++j2)
#pragma unroll
    for (int r = 0; r < 4; ++r) {
      const int q = q0 + wv * 16 + lg * 4 + r;
      ctxg[(size_t)q * Hd + j2 * 16 + lc] = f2b(cacc[j2][r]);
    }
#undef STAGE_K
#undef STAGE_V
#undef FENCE
}

// ---------------------------------------------------------------------------
extern "C" void kernel_launch(void* const* d_in, const int* in_sizes, int n_in,
                              void* d_out, int out_size, void* d_ws,
                              size_t ws_size, hipStream_t stream) {
  const float* x = (const float*)d_in[0];
  const int* mask = (const int*)d_in[1];
  const float* Wq = (const float*)d_in[2];
  const float* bq = (const float*)d_in[3];
  const float* Wk = (const float*)d_in[4];
  const float* bk = (const float*)d_in[5];
  const float* Wv = (const float*)d_in[6];
  const float* bv = (const float*)d_in[7];
  const float* Wo = (const float*)d_in[8];
  const float* bo = (const float*)d_in[9];
  const float* W1 = (const float*)d_in[10];
  const float* b1 = (const float*)d_in[11];
  const float* W2 = (const float*)d_in[12];
  const float* b2 = (const float*)d_in[13];

  float* out = (float*)d_out;
  float* attn = out + (size_t)BT * Dd;

  char* w = (char*)d_ws;
  u16* xb = (u16*)w;      w += (size_t)BT * Dd * 2;
  u16* wqkvT = (u16*)w;   w += (size_t)Dd * 2304 * 2;
  u16* woT = (u16*)w;     w += (size_t)Dd * Dd * 2;
  u16* w1T = (u16*)w;     w += (size_t)Dd * Df * 2;
  u16* w2T = (u16*)w;     w += (size_t)Df * Dd * 2;
  float* biasc = (float*)w;            w += 2304 * 4;
  unsigned int* mwords = (unsigned int*)w; w += 256 * 4;
  u16* qb = (u16*)w;      w += (size_t)BT * Dd * 2;
  u16* kb = (u16*)w;      w += (size_t)BT * Dd * 2;
  u16* vtb = (u16*)w;     w += (size_t)BT * Dd * 2;
  u16* ctxb = (u16*)w;    w += (size_t)BT * Dd * 2;
  u16* ff1b = (u16*)w;    w += (size_t)BT * Df * 2;
  float* h = (float*)qb;  // overlays qb+kb (dead after attn_fused)
  u16* hb = vtb;          // overlays vtb (dead after attn_fused)

  dim3 blk(256);

  // all prep in one launch
  prep_all<<<dim3(9994), blk, 0, stream>>>(x, Wq, Wk, Wv, Wo, W1, W2, bq, bk,
                                           bv, mask, xb, wqkvT, woT, w1T, w2T,
                                           biasc, mwords);

  // fused QKV projection (N = 2304)
  mgemm<5><<<dim3(18, 64), blk, 0, stream>>>(xb, wqkvT, biasc, nullptr, qb, kb,
                                             vtb, Dd, 2304);

  // fused attention: attn (written once, coalesced, nt, floating) + ctx
  attn_fused<<<dim3(32, 48), blk, 0, stream>>>(qb, kb, vtb, mwords, attn, ctxb);

  // h = x + ctx@Wo + bo   (fp32 + bf16)
  mgemm<2><<<dim3(6, 64), blk, 0, stream>>>(ctxb, woT, bo, x, h, hb, nullptr,
                                            Dd, Dd);

  // ff1 = gelu(h@W1 + b1) bf16
  mgemm<3><<<dim3(24, 64), blk, 0, stream>>>(hb, w1T, b1, nullptr, ff1b,
                                             nullptr, nullptr, Dd, Df);

  // out = h + ff1@W2 + b2
  mgemm<4><<<dim3(6, 64), blk, 0, stream>>>(ff1b, w2T, b2, h, out, nullptr,
                                            nullptr, Df, Dd);
}